// Round 2
// baseline (1119.702 us; speedup 1.0000x reference)
//
#include <hip/hip_runtime.h>
#include <stdint.h>

// ============================================================================
// ScaledHeadBlock fused pipeline for MI355X (gfx950).
//
//  1. LN1: x -> h (fp32)                                   h  @ ws[128,160)MB
//  2. k,q = h @ W{k,q}^T (split-bf16 MFMA, fp32 out)       k[0,64) q[64,128)
//     vT  = (h @ Wv^T)^T (split-bf16 MFMA, bf16 transposed out) vT[192,224)
//  3. sT[b][j][i] = dot(q_j,k_i) (split GEMM, batched)     sT[128,192) (h dead)
//  4. column softmax (mask i>=j), in-place bf16 wT
//  5. transpose wT -> w[i][j] bf16                         w[64,96)   (q dead)
//  6. att = w @ vT^T (bf16 GEMM, batched)                  att[96,128)
//  7. d_out = x + relu(att @ Wl^T + bl)  (fp32)            Wlb[0,4) W1b[4,12) W2b[12,20)
//  8. LN2: d_out -> h2 (bf16)                              h2[20,36)
//  9. ff1 = relu(h2 @ W1^T + b1) (bf16)                    ff1[128,192) (sT dead)
// 10. d_out += ff1 @ W2^T + b2
//  Peak workspace: 224 MB.
// ============================================================================

typedef __attribute__((ext_vector_type(8))) short bf16x8;
typedef __attribute__((ext_vector_type(4))) float floatx4;

#define DEVFN static __device__ __forceinline__

DEVFN unsigned short f2bf(float f) {
  union { float f; unsigned u; } v; v.f = f;
  return (unsigned short)((v.u + 0x7fffu + ((v.u >> 16) & 1u)) >> 16);
}
DEVFN float bf2f(unsigned short u) {
  union { unsigned u; float f; } v; v.u = ((unsigned)u) << 16; return v.f;
}
DEVFN void gload_lds16(const void* g, void* l) {
  __builtin_amdgcn_global_load_lds(
      (const __attribute__((address_space(1))) void*)g,
      (__attribute__((address_space(3))) void*)l, 16, 0, 0);
}

// ---------------- LayerNorm over rows of 1024 floats ----------------
template<int OUTBF>
__global__ __launch_bounds__(256)
void layernorm_k(const float* __restrict__ X, const float* __restrict__ g,
                 const float* __restrict__ be, void* __restrict__ out)
{
  const int tid = threadIdx.x;
  const long base = (long)blockIdx.x * 1024 + tid * 4;
  __shared__ float red[4];
  float4 xv = *(const float4*)&X[base];
  float s = xv.x + xv.y + xv.z + xv.w;
  #pragma unroll
  for (int o = 32; o; o >>= 1) s += __shfl_down(s, o);
  if ((tid & 63) == 0) red[tid >> 6] = s;
  __syncthreads();
  const float mu = (red[0] + red[1] + red[2] + red[3]) * (1.f / 1024.f);
  __syncthreads();
  const float d0 = xv.x - mu, d1 = xv.y - mu, d2 = xv.z - mu, d3 = xv.w - mu;
  float ss = d0*d0 + d1*d1 + d2*d2 + d3*d3;
  #pragma unroll
  for (int o = 32; o; o >>= 1) ss += __shfl_down(ss, o);
  if ((tid & 63) == 0) red[tid >> 6] = ss;
  __syncthreads();
  const float var = (red[0] + red[1] + red[2] + red[3]) * (1.f / 1024.f);
  const float inv = rsqrtf(var + 1e-5f);
  float4 gv = *(const float4*)&g[tid * 4];
  float4 bv = *(const float4*)&be[tid * 4];
  const float y0 = d0 * inv * gv.x + bv.x;
  const float y1 = d1 * inv * gv.y + bv.y;
  const float y2 = d2 * inv * gv.z + bv.z;
  const float y3 = d3 * inv * gv.w + bv.w;
  if (OUTBF) {
    ushort4 o; o.x = f2bf(y0); o.y = f2bf(y1); o.z = f2bf(y2); o.w = f2bf(y3);
    *(ushort4*)((unsigned short*)out + base) = o;
  } else {
    float4 o; o.x = y0; o.y = y1; o.z = y2; o.w = y3;
    *(float4*)((float*)out + base) = o;
  }
}

// ---------------- bf16 BT-GEMM: C[m][n] = act(sum_k A[m][k]*B[n][k] + bias + res)
// 128x128 tile, BK=32, 256 threads (4 waves, 2x2 of 64x64), global_load_lds staging.
template<int OUTBF, int BIAS, int RELU, int RES>
__global__ __launch_bounds__(256)
void gemm_bt(const unsigned short* __restrict__ A,
             const unsigned short* __restrict__ B,
             void* __restrict__ Cv,
             const float* __restrict__ bias,
             const float* __restrict__ res,
             int K, int lda, int ldb, int ldc,
             long sAz, long sBz, long sCz)
{
  __shared__ unsigned short As[128 * 32];
  __shared__ unsigned short Bs[128 * 32];
  const int z = blockIdx.z;
  const unsigned short* Ap = A + (long)z * sAz;
  const unsigned short* Bp = B + (long)z * sBz;
  const int m0 = blockIdx.y * 128, n0 = blockIdx.x * 128;
  const int tid = threadIdx.x, lane = tid & 63, wave = tid >> 6;
  const int wm = (wave >> 1) * 64, wn = (wave & 1) * 64;
  const int crow = lane >> 2;          // row within 16-row chunk
  const int ccol = (lane & 3) * 8;     // col (elements) within 32-wide row
  const int kq = (lane >> 4) * 8, rr = lane & 15;

  floatx4 acc[4][4];
  #pragma unroll
  for (int i = 0; i < 4; ++i)
    #pragma unroll
    for (int j = 0; j < 4; ++j) {
      acc[i][j][0] = 0.f; acc[i][j][1] = 0.f; acc[i][j][2] = 0.f; acc[i][j][3] = 0.f;
    }

  for (int k0 = 0; k0 < K; k0 += 32) {
    #pragma unroll
    for (int c = 0; c < 2; ++c) {
      const int chunk = wave + c * 4;            // wave-uniform
      const int row = chunk * 16 + crow;
      gload_lds16(Ap + (long)(m0 + row) * lda + k0 + ccol, &As[chunk * 512]);
      gload_lds16(Bp + (long)(n0 + row) * ldb + k0 + ccol, &Bs[chunk * 512]);
    }
    __syncthreads();
    bf16x8 af[4], bfr[4];
    #pragma unroll
    for (int i = 0; i < 4; ++i) {
      af[i]  = *(const bf16x8*)&As[(wm + i * 16 + rr) * 32 + kq];
      bfr[i] = *(const bf16x8*)&Bs[(wn + i * 16 + rr) * 32 + kq];
    }
    #pragma unroll
    for (int mi = 0; mi < 4; ++mi)
      #pragma unroll
      for (int ni = 0; ni < 4; ++ni)
        acc[mi][ni] = __builtin_amdgcn_mfma_f32_16x16x32_bf16(af[mi], bfr[ni], acc[mi][ni], 0, 0, 0);
    __syncthreads();
  }

  const int er = lane >> 4, ec = lane & 15;
  #pragma unroll
  for (int mi = 0; mi < 4; ++mi)
    #pragma unroll
    for (int ni = 0; ni < 4; ++ni) {
      const int gcol = n0 + wn + ni * 16 + ec;
      const float bv = BIAS ? bias[gcol] : 0.f;
      #pragma unroll
      for (int e = 0; e < 4; ++e) {
        const int grow = m0 + wm + mi * 16 + er * 4 + e;
        const long off = (long)z * sCz + (long)grow * ldc + gcol;
        float val = acc[mi][ni][e] + bv;
        if (RELU) val = fmaxf(val, 0.f);
        if (RES) val += res[off];
        if (OUTBF) ((unsigned short*)Cv)[off] = f2bf(val);
        else       ((float*)Cv)[off] = val;
      }
    }
}

// ---------------- fp32-input split-bf16 BT-GEMM (hi/lo, 3 MFMA per frag).
// TRANSOUT=0: fp32 C[m][n].  TRANSOUT=1: bf16 C[n][m] (ushort4 stores).
template<int TRANSOUT>
__global__ __launch_bounds__(256)
void gemm_bt_f32split(const float* __restrict__ A, const float* __restrict__ B,
                      void* __restrict__ Cv, int K, int lda, int ldb, int ldc,
                      long sAz, long sBz, long sCz)
{
  __shared__ unsigned short Ah[128 * 32];
  __shared__ unsigned short Al[128 * 32];
  __shared__ unsigned short Bh[128 * 32];
  __shared__ unsigned short Bl[128 * 32];
  const int z = blockIdx.z;
  const float* Ap = A + (long)z * sAz;
  const float* Bp = B + (long)z * sBz;
  const int m0 = blockIdx.y * 128, n0 = blockIdx.x * 128;
  const int tid = threadIdx.x, lane = tid & 63, wave = tid >> 6;
  const int wm = (wave >> 1) * 64, wn = (wave & 1) * 64;
  const int kq = (lane >> 4) * 8, rr = lane & 15;

  floatx4 acc[4][4];
  #pragma unroll
  for (int i = 0; i < 4; ++i)
    #pragma unroll
    for (int j = 0; j < 4; ++j) {
      acc[i][j][0] = 0.f; acc[i][j][1] = 0.f; acc[i][j][2] = 0.f; acc[i][j][3] = 0.f;
    }

  for (int k0 = 0; k0 < K; k0 += 32) {
    #pragma unroll
    for (int it = 0; it < 4; ++it) {
      const int qd = tid + 256 * it;
      const int row = qd >> 3;
      const int c = (qd & 7) * 4;
      float4 a = *(const float4*)&Ap[(long)(m0 + row) * lda + k0 + c];
      float4 b = *(const float4*)&Bp[(long)(n0 + row) * ldb + k0 + c];
      ushort4 ah, al, bh, bl;
      ah.x = f2bf(a.x); al.x = f2bf(a.x - bf2f(ah.x));
      ah.y = f2bf(a.y); al.y = f2bf(a.y - bf2f(ah.y));
      ah.z = f2bf(a.z); al.z = f2bf(a.z - bf2f(ah.z));
      ah.w = f2bf(a.w); al.w = f2bf(a.w - bf2f(ah.w));
      bh.x = f2bf(b.x); bl.x = f2bf(b.x - bf2f(bh.x));
      bh.y = f2bf(b.y); bl.y = f2bf(b.y - bf2f(bh.y));
      bh.z = f2bf(b.z); bl.z = f2bf(b.z - bf2f(bh.z));
      bh.w = f2bf(b.w); bl.w = f2bf(b.w - bf2f(bh.w));
      *(ushort4*)&Ah[row * 32 + c] = ah;
      *(ushort4*)&Al[row * 32 + c] = al;
      *(ushort4*)&Bh[row * 32 + c] = bh;
      *(ushort4*)&Bl[row * 32 + c] = bl;
    }
    __syncthreads();
    bf16x8 fah[4], fal[4], fbh[4], fbl[4];
    #pragma unroll
    for (int i = 0; i < 4; ++i) {
      fah[i] = *(const bf16x8*)&Ah[(wm + i * 16 + rr) * 32 + kq];
      fal[i] = *(const bf16x8*)&Al[(wm + i * 16 + rr) * 32 + kq];
      fbh[i] = *(const bf16x8*)&Bh[(wn + i * 16 + rr) * 32 + kq];
      fbl[i] = *(const bf16x8*)&Bl[(wn + i * 16 + rr) * 32 + kq];
    }
    #pragma unroll
    for (int mi = 0; mi < 4; ++mi)
      #pragma unroll
      for (int ni = 0; ni < 4; ++ni) {
        acc[mi][ni] = __builtin_amdgcn_mfma_f32_16x16x32_bf16(fah[mi], fbh[ni], acc[mi][ni], 0, 0, 0);
        acc[mi][ni] = __builtin_amdgcn_mfma_f32_16x16x32_bf16(fah[mi], fbl[ni], acc[mi][ni], 0, 0, 0);
        acc[mi][ni] = __builtin_amdgcn_mfma_f32_16x16x32_bf16(fal[mi], fbh[ni], acc[mi][ni], 0, 0, 0);
      }
    __syncthreads();
  }

  const int er = lane >> 4, ec = lane & 15;
  #pragma unroll
  for (int mi = 0; mi < 4; ++mi)
    #pragma unroll
    for (int ni = 0; ni < 4; ++ni) {
      const int gcol = n0 + wn + ni * 16 + ec;
      if (TRANSOUT) {
        // C^T bf16: address = gcol*ldc + grow; e=0..3 are contiguous rows.
        const int grow0 = m0 + wm + mi * 16 + er * 4;
        ushort4 o;
        o.x = f2bf(acc[mi][ni][0]); o.y = f2bf(acc[mi][ni][1]);
        o.z = f2bf(acc[mi][ni][2]); o.w = f2bf(acc[mi][ni][3]);
        *(ushort4*)&((unsigned short*)Cv)[(long)z * sCz + (long)gcol * ldc + grow0] = o;
      } else {
        #pragma unroll
        for (int e = 0; e < 4; ++e) {
          const int grow = m0 + wm + mi * 16 + er * 4 + e;
          ((float*)Cv)[(long)z * sCz + (long)grow * ldc + gcol] = acc[mi][ni][e];
        }
      }
    }
}

// ---------------- column softmax: row-softmax of sT[b][j][:], mask i>=j,
// in-place write of bf16 wT row into the fp32 row's storage.
__global__ __launch_bounds__(256)
void col_softmax(float* __restrict__ sT)
{
  const int T = 2048;
  const int j = blockIdx.x;
  float* row = sT + ((long)blockIdx.y * T + j) * T;
  const int tid = threadIdx.x;
  __shared__ float red[4];
  float lv[8];
  float lmax = -3.0e38f;
  #pragma unroll
  for (int p = 0; p < 2; ++p) {
    float4 v = *(const float4*)&row[tid * 4 + p * 1024];
    const int i0 = tid * 4 + p * 1024;
    lv[p * 4 + 0] = 32.f * v.x; if (i0 + 0 >= j) lmax = fmaxf(lmax, lv[p * 4 + 0]);
    lv[p * 4 + 1] = 32.f * v.y; if (i0 + 1 >= j) lmax = fmaxf(lmax, lv[p * 4 + 1]);
    lv[p * 4 + 2] = 32.f * v.z; if (i0 + 2 >= j) lmax = fmaxf(lmax, lv[p * 4 + 2]);
    lv[p * 4 + 3] = 32.f * v.w; if (i0 + 3 >= j) lmax = fmaxf(lmax, lv[p * 4 + 3]);
  }
  #pragma unroll
  for (int o = 32; o; o >>= 1) lmax = fmaxf(lmax, __shfl_down(lmax, o));
  if ((tid & 63) == 0) red[tid >> 6] = lmax;
  __syncthreads();
  const float m = fmaxf(fmaxf(red[0], red[1]), fmaxf(red[2], red[3]));
  __syncthreads();
  float zs = 0.f;
  #pragma unroll
  for (int p = 0; p < 2; ++p)
    #pragma unroll
    for (int q = 0; q < 4; ++q) {
      const int i = tid * 4 + p * 1024 + q;
      if (i >= j) zs += __expf(lv[p * 4 + q] - m);
    }
  #pragma unroll
  for (int o = 32; o; o >>= 1) zs += __shfl_down(zs, o);
  if ((tid & 63) == 0) red[tid >> 6] = zs;
  __syncthreads();
  const float rz = 1.f / (red[0] + red[1] + red[2] + red[3]);
  unsigned short* wrow = (unsigned short*)row;
  #pragma unroll
  for (int p = 0; p < 2; ++p) {
    ushort4 o;
    #pragma unroll
    for (int q = 0; q < 4; ++q) {
      const int i = tid * 4 + p * 1024 + q;
      const float wv = (i >= j) ? __expf(lv[p * 4 + q] - m) * rz : 0.f;
      ((unsigned short*)&o)[q] = f2bf(wv);
    }
    *(ushort4*)&wrow[tid * 4 + p * 1024] = o;
  }
}

// ---------------- 64x64 tiled bf16 transpose ----------------
__global__ __launch_bounds__(256)
void transpose_bf16(const unsigned short* __restrict__ in, unsigned short* __restrict__ out,
                    int ldin, int ldout, long sInZ, long sOutZ)
{
  __shared__ unsigned short tile[64][65];
  const int z = blockIdx.z;
  const int i0 = blockIdx.x * 64;  // in-col
  const int j0 = blockIdx.y * 64;  // in-row
  const int t = threadIdx.x;
  const int r = t >> 4;            // 0..15
  const int c = (t & 15) * 4;      // 0..60
  #pragma unroll
  for (int p = 0; p < 4; ++p) {
    const int row = j0 + r + p * 16;
    const unsigned short* ip = in + z * sInZ + (long)row * ldin + i0 + c;
    ushort4 v = *(const ushort4*)ip;
    tile[r + p * 16][c + 0] = v.x;
    tile[r + p * 16][c + 1] = v.y;
    tile[r + p * 16][c + 2] = v.z;
    tile[r + p * 16][c + 3] = v.w;
  }
  __syncthreads();
  #pragma unroll
  for (int p = 0; p < 4; ++p) {
    const int orow = i0 + r + p * 16;
    ushort4 o;
    o.x = tile[c + 0][r + p * 16];
    o.y = tile[c + 1][r + p * 16];
    o.z = tile[c + 2][r + p * 16];
    o.w = tile[c + 3][r + p * 16];
    *(ushort4*)&out[(long)z * sOutZ + (long)orow * ldout + j0 + c] = o;
  }
}

// ---------------- fp32 -> bf16 cast ----------------
__global__ __launch_bounds__(256)
void cast_f32_bf16(const float* __restrict__ in, unsigned short* __restrict__ out, int n4)
{
  const int i = blockIdx.x * 256 + threadIdx.x;
  if (i < n4) {
    float4 v = *(const float4*)&in[i * 4];
    ushort4 o; o.x = f2bf(v.x); o.y = f2bf(v.y); o.z = f2bf(v.z); o.w = f2bf(v.w);
    *(ushort4*)&out[i * 4] = o;
  }
}

// ============================================================================
extern "C" void kernel_launch(void* const* d_in, const int* in_sizes, int n_in,
                              void* d_out, int out_size, void* d_ws, size_t ws_size,
                              hipStream_t stream)
{
  (void)in_sizes; (void)n_in; (void)out_size; (void)ws_size;
  const int BT = 8192;           // B*T = 4*2048
  const long TT = 2048L * 2048;  // per-batch matrix elements

  const float* x   = (const float*)d_in[0];
  const float* Wk  = (const float*)d_in[1];
  const float* Wq  = (const float*)d_in[2];
  const float* Wv  = (const float*)d_in[3];
  const float* Wl  = (const float*)d_in[4];
  const float* bl  = (const float*)d_in[5];
  const float* W1  = (const float*)d_in[6];
  const float* b1  = (const float*)d_in[7];
  const float* W2  = (const float*)d_in[8];
  const float* b2  = (const float*)d_in[9];
  const float* g1  = (const float*)d_in[10];
  const float* be1 = (const float*)d_in[11];
  const float* g2  = (const float*)d_in[12];
  const float* be2 = (const float*)d_in[13];
  float* out = (float*)d_out;

  // ---- workspace layout (time-aliased, peak 224 MB) ----
  char* ws = (char*)d_ws;
  const size_t MB = 1024 * 1024;
  float* k  = (float*)(ws + 0);             // [8192][2048] f32, 64MB, dies after scores
  float* q  = (float*)(ws + 64 * MB);       // [8192][2048] f32, 64MB, dies after scores
  float* h  = (float*)(ws + 128 * MB);      // [8192][1024] f32, 32MB, dies after kqv
  float* sT = (float*)(ws + 128 * MB);      // 4x[2048][2048] f32, 64MB (over dead h)
  unsigned short* vT  = (unsigned short*)(ws + 192 * MB);  // [2048][8192] bf16, 32MB
  unsigned short* w   = (unsigned short*)(ws + 64 * MB);   // 4x[2048][2048] bf16 (over dead q)
  unsigned short* att = (unsigned short*)(ws + 96 * MB);   // [8192][2048] bf16
  unsigned short* Wlb = (unsigned short*)(ws + 0);         // 4MB (over dead k)
  unsigned short* W1b = (unsigned short*)(ws + 4 * MB);    // 8MB
  unsigned short* W2b = (unsigned short*)(ws + 12 * MB);   // 8MB
  unsigned short* h2  = (unsigned short*)(ws + 20 * MB);   // [8192][1024] bf16, 16MB
  unsigned short* ff1 = (unsigned short*)(ws + 128 * MB);  // [8192][4096] bf16, 64MB (over dead sT)

  // 1. LN1
  layernorm_k<0><<<dim3(BT), 256, 0, stream>>>(x, g1, be1, (void*)h);

  // 2. k, q projections (split precision, fp32 out); v -> vT directly (bf16, transposed)
  {
    dim3 g(2048 / 128, BT / 128, 1);  // (16, 64)
    gemm_bt_f32split<0><<<g, 256, 0, stream>>>(h, Wk, (void*)k, 1024, 1024, 1024, 2048, 0, 0, 0);
    gemm_bt_f32split<0><<<g, 256, 0, stream>>>(h, Wq, (void*)q, 1024, 1024, 1024, 2048, 0, 0, 0);
    gemm_bt_f32split<1><<<g, 256, 0, stream>>>(h, Wv, (void*)vT, 1024, 1024, 1024, 8192, 0, 0, 0);
  }

  // 3. sT[b][j][i] = dot(q_j, k_i)  (batched, split precision)
  gemm_bt_f32split<0><<<dim3(16, 16, 4), 256, 0, stream>>>(q, k, (void*)sT,
                                                           2048, 2048, 2048, 2048, TT, TT, TT);

  // 4. column softmax (mask i>=j), in-place bf16 wT
  col_softmax<<<dim3(2048, 4), 256, 0, stream>>>(sT);

  // 5. transpose wT -> w  (input rows have bf16 ld 4096 = old fp32 rows)
  transpose_bf16<<<dim3(32, 32, 4), 256, 0, stream>>>((const unsigned short*)sT, w,
                                                      4096, 2048, 2048L * 4096, TT);

  // weight casts (over dead k)
  cast_f32_bf16<<<dim3(2097152 / 4 / 256), 256, 0, stream>>>(Wl, Wlb, 2097152 / 4);
  cast_f32_bf16<<<dim3(4194304 / 4 / 256), 256, 0, stream>>>(W1, W1b, 4194304 / 4);
  cast_f32_bf16<<<dim3(4194304 / 4 / 256), 256, 0, stream>>>(W2, W2b, 4194304 / 4);

  // 6. att = w @ vT^T (batched; vT row d of batch z starts at d*8192 + z*2048)
  gemm_bt<1, 0, 0, 0><<<dim3(16, 16, 4), 256, 0, stream>>>(w, vT, (void*)att, nullptr, nullptr,
                                                           2048, 2048, 8192, 2048, TT, 2048, TT);

  // 7. d_out = x + relu(att @ Wl^T + bl)
  gemm_bt<0, 1, 1, 1><<<dim3(8, 64, 1), 256, 0, stream>>>(att, Wlb, (void*)out, bl, x,
                                                          2048, 2048, 2048, 1024, 0, 0, 0);

  // 8. LN2
  layernorm_k<1><<<dim3(BT), 256, 0, stream>>>(out, g2, be2, (void*)h2);

  // 9. ff1 = relu(h2 @ W1^T + b1)
  gemm_bt<1, 1, 1, 0><<<dim3(32, 64, 1), 256, 0, stream>>>(h2, W1b, (void*)ff1, b1, nullptr,
                                                           1024, 1024, 1024, 4096, 0, 0, 0);

  // 10. d_out += ff1 @ W2^T + b2
  gemm_bt<0, 1, 0, 1><<<dim3(8, 64, 1), 256, 0, stream>>>(ff1, W2b, (void*)out, b2, out,
                                                          4096, 4096, 4096, 1024, 0, 0, 0);
}

// Round 3
// 969.474 us; speedup vs baseline: 1.1550x; 1.1550x over previous
//
#include <hip/hip_runtime.h>
#include <stdint.h>

// ============================================================================
// ScaledHeadBlock fused pipeline for MI355X (gfx950).
//
// Precision scheme: the k/q/scores path needs ~17 mantissa bits (logit std
// ~480, column-softmax is near-argmax). All high-precision values are stored
// as SPLIT bf16 (hi + lo), and GEMMs on them run 3 MFMAs per fragment pair
// (hh + hl + lh) on pre-split operands -- no in-loop conversion VALU work.
// Post-softmax path (v, att, FFN) is plain bf16.
//
//  1. LN1: x -> hhi,hlo (bf16 split)
//     Wk,Wq -> hi/lo bf16; Wv -> bf16
//  2. khi/klo = h @ Wk^T   (split GEMM, split-out epilogue)   qhi/qlo likewise
//     vT = (h @ Wv^T)^T    (plain bf16 GEMM, transposed-out)
//  3. sT[b][j][i] = dot(q_j,k_i)  (split GEMM, fp32 out)
//  4. column softmax (mask i>=j), in-place bf16 wT
//  5. transpose wT -> w[i][j] bf16
//  6. att = w @ vT^T (bf16 GEMM, batched)
//  7. d_out = x + relu(att @ Wl^T + bl)
//  8. LN2 -> h2 (bf16)
//  9. ff1 = relu(h2 @ W1^T + b1)
// 10. d_out += ff1 @ W2^T + b2
//
// Workspace (MB, peak 224):
//   khi[0,32) klo[32,64) qhi[64,96) qlo[96,128)
//   hhi[128,144) hlo[144,160) WkWqWv-splits[160,184)   } dead before sT
//   sT[128,192) fp32                                    } then ff1[128,192)
//   vT[192,224)
//   after scores: Wlb[0,4) W1b[4,12) W2b[12,20) h2[20,36)
//   w[64,96) att[96,128)
// ============================================================================

typedef __attribute__((ext_vector_type(8))) short bf16x8;
typedef __attribute__((ext_vector_type(4))) float floatx4;

#define DEVFN static __device__ __forceinline__

DEVFN unsigned short f2bf(float f) {
  union { float f; unsigned u; } v; v.f = f;
  return (unsigned short)((v.u + 0x7fffu + ((v.u >> 16) & 1u)) >> 16);
}
DEVFN float bf2f(unsigned short u) {
  union { unsigned u; float f; } v; v.u = ((unsigned)u) << 16; return v.f;
}
DEVFN void gload_lds16(const void* g, void* l) {
  __builtin_amdgcn_global_load_lds(
      (const __attribute__((address_space(1))) void*)g,
      (__attribute__((address_space(3))) void*)l, 16, 0, 0);
}

// ---------------- LayerNorm over rows of 1024 floats ----------------
// OUTMODE: 1 = single bf16, 2 = split hi/lo bf16
template<int OUTMODE>
__global__ __launch_bounds__(256)
void layernorm_k(const float* __restrict__ X, const float* __restrict__ g,
                 const float* __restrict__ be, unsigned short* __restrict__ o_hi,
                 unsigned short* __restrict__ o_lo)
{
  const int tid = threadIdx.x;
  const long base = (long)blockIdx.x * 1024 + tid * 4;
  __shared__ float red[4];
  float4 xv = *(const float4*)&X[base];
  float s = xv.x + xv.y + xv.z + xv.w;
  #pragma unroll
  for (int o = 32; o; o >>= 1) s += __shfl_down(s, o);
  if ((tid & 63) == 0) red[tid >> 6] = s;
  __syncthreads();
  const float mu = (red[0] + red[1] + red[2] + red[3]) * (1.f / 1024.f);
  __syncthreads();
  const float d0 = xv.x - mu, d1 = xv.y - mu, d2 = xv.z - mu, d3 = xv.w - mu;
  float ss = d0*d0 + d1*d1 + d2*d2 + d3*d3;
  #pragma unroll
  for (int o = 32; o; o >>= 1) ss += __shfl_down(ss, o);
  if ((tid & 63) == 0) red[tid >> 6] = ss;
  __syncthreads();
  const float var = (red[0] + red[1] + red[2] + red[3]) * (1.f / 1024.f);
  const float inv = rsqrtf(var + 1e-5f);
  float4 gv = *(const float4*)&g[tid * 4];
  float4 bv = *(const float4*)&be[tid * 4];
  float y[4];
  y[0] = d0 * inv * gv.x + bv.x;
  y[1] = d1 * inv * gv.y + bv.y;
  y[2] = d2 * inv * gv.z + bv.z;
  y[3] = d3 * inv * gv.w + bv.w;
  ushort4 hi, lo;
  #pragma unroll
  for (int e = 0; e < 4; ++e) {
    const unsigned short h = f2bf(y[e]);
    ((unsigned short*)&hi)[e] = h;
    if (OUTMODE == 2) ((unsigned short*)&lo)[e] = f2bf(y[e] - bf2f(h));
  }
  *(ushort4*)&o_hi[base] = hi;
  if (OUTMODE == 2) *(ushort4*)&o_lo[base] = lo;
}

// ---------------- bf16 BT-GEMM: C[m][n] = act(sum_k A[m][k]*B[n][k] + bias + res)
// 128x128 tile, BK=32, 256 threads (4 waves, 2x2 of 64x64), global_load_lds staging.
// TROUT=1: write bf16 C^T (C[n][m]) via ushort4, ignore BIAS/RELU/RES.
template<int OUTBF, int BIAS, int RELU, int RES, int TROUT>
__global__ __launch_bounds__(256)
void gemm_bt(const unsigned short* __restrict__ A,
             const unsigned short* __restrict__ B,
             void* __restrict__ Cv,
             const float* __restrict__ bias,
             const float* __restrict__ res,
             int K, int lda, int ldb, int ldc,
             long sAz, long sBz, long sCz)
{
  __shared__ unsigned short As[128 * 32];
  __shared__ unsigned short Bs[128 * 32];
  const int z = blockIdx.z;
  const unsigned short* Ap = A + (long)z * sAz;
  const unsigned short* Bp = B + (long)z * sBz;
  const int m0 = blockIdx.y * 128, n0 = blockIdx.x * 128;
  const int tid = threadIdx.x, lane = tid & 63, wave = tid >> 6;
  const int wm = (wave >> 1) * 64, wn = (wave & 1) * 64;
  const int crow = lane >> 2;          // row within 16-row chunk
  const int ccol = (lane & 3) * 8;     // col (elements) within 32-wide row
  const int kq = (lane >> 4) * 8, rr = lane & 15;

  floatx4 acc[4][4];
  #pragma unroll
  for (int i = 0; i < 4; ++i)
    #pragma unroll
    for (int j = 0; j < 4; ++j) {
      acc[i][j][0] = 0.f; acc[i][j][1] = 0.f; acc[i][j][2] = 0.f; acc[i][j][3] = 0.f;
    }

  for (int k0 = 0; k0 < K; k0 += 32) {
    #pragma unroll
    for (int c = 0; c < 2; ++c) {
      const int chunk = wave + c * 4;            // wave-uniform
      const int row = chunk * 16 + crow;
      gload_lds16(Ap + (long)(m0 + row) * lda + k0 + ccol, &As[chunk * 512]);
      gload_lds16(Bp + (long)(n0 + row) * ldb + k0 + ccol, &Bs[chunk * 512]);
    }
    __syncthreads();
    bf16x8 af[4], bfr[4];
    #pragma unroll
    for (int i = 0; i < 4; ++i) {
      af[i]  = *(const bf16x8*)&As[(wm + i * 16 + rr) * 32 + kq];
      bfr[i] = *(const bf16x8*)&Bs[(wn + i * 16 + rr) * 32 + kq];
    }
    #pragma unroll
    for (int mi = 0; mi < 4; ++mi)
      #pragma unroll
      for (int ni = 0; ni < 4; ++ni)
        acc[mi][ni] = __builtin_amdgcn_mfma_f32_16x16x32_bf16(af[mi], bfr[ni], acc[mi][ni], 0, 0, 0);
    __syncthreads();
  }

  const int er = lane >> 4, ec = lane & 15;
  #pragma unroll
  for (int mi = 0; mi < 4; ++mi)
    #pragma unroll
    for (int ni = 0; ni < 4; ++ni) {
      const int gcol = n0 + wn + ni * 16 + ec;
      if (TROUT) {
        const int grow0 = m0 + wm + mi * 16 + er * 4;
        ushort4 o;
        o.x = f2bf(acc[mi][ni][0]); o.y = f2bf(acc[mi][ni][1]);
        o.z = f2bf(acc[mi][ni][2]); o.w = f2bf(acc[mi][ni][3]);
        *(ushort4*)&((unsigned short*)Cv)[(long)z * sCz + (long)gcol * ldc + grow0] = o;
      } else {
        const float bv = BIAS ? bias[gcol] : 0.f;
        #pragma unroll
        for (int e = 0; e < 4; ++e) {
          const int grow = m0 + wm + mi * 16 + er * 4 + e;
          const long off = (long)z * sCz + (long)grow * ldc + gcol;
          float val = acc[mi][ni][e] + bv;
          if (RELU) val = fmaxf(val, 0.f);
          if (RES) val += res[off];
          if (OUTBF) ((unsigned short*)Cv)[off] = f2bf(val);
          else       ((float*)Cv)[off] = val;
        }
      }
    }
}

// ---------------- split-bf16 BT-GEMM on PRE-SPLIT operands ----------------
// C = (Ahi+Alo) @ (Bhi+Blo)^T via 3 MFMAs/pair (hh + hl + lh), all staging
// through global_load_lds (no VALU conversions in the loop).
// OUTMODE 0: fp32 C.  OUTMODE 1: split bf16 Chi/Clo.
template<int OUTMODE>
__global__ __launch_bounds__(256)
void gemm_split2(const unsigned short* __restrict__ Ahi, const unsigned short* __restrict__ Alo,
                 const unsigned short* __restrict__ Bhi, const unsigned short* __restrict__ Blo,
                 void* __restrict__ C0, unsigned short* __restrict__ Clo,
                 int K, int lda, int ldb, int ldc,
                 long sAz, long sBz, long sCz)
{
  __shared__ unsigned short AhiS[128 * 32];
  __shared__ unsigned short AloS[128 * 32];
  __shared__ unsigned short BhiS[128 * 32];
  __shared__ unsigned short BloS[128 * 32];
  const int z = blockIdx.z;
  const unsigned short* Ahp = Ahi + (long)z * sAz;
  const unsigned short* Alp = Alo + (long)z * sAz;
  const unsigned short* Bhp = Bhi + (long)z * sBz;
  const unsigned short* Blp = Blo + (long)z * sBz;
  const int m0 = blockIdx.y * 128, n0 = blockIdx.x * 128;
  const int tid = threadIdx.x, lane = tid & 63, wave = tid >> 6;
  const int wm = (wave >> 1) * 64, wn = (wave & 1) * 64;
  const int crow = lane >> 2;
  const int ccol = (lane & 3) * 8;
  const int kq = (lane >> 4) * 8, rr = lane & 15;

  floatx4 acc[4][4];
  #pragma unroll
  for (int i = 0; i < 4; ++i)
    #pragma unroll
    for (int j = 0; j < 4; ++j) {
      acc[i][j][0] = 0.f; acc[i][j][1] = 0.f; acc[i][j][2] = 0.f; acc[i][j][3] = 0.f;
    }

  for (int k0 = 0; k0 < K; k0 += 32) {
    #pragma unroll
    for (int c = 0; c < 2; ++c) {
      const int chunk = wave + c * 4;            // wave-uniform
      const int row = chunk * 16 + crow;
      const int loff = chunk * 512;
      const long ao = (long)(m0 + row) * lda + k0 + ccol;
      const long bo = (long)(n0 + row) * ldb + k0 + ccol;
      gload_lds16(Ahp + ao, &AhiS[loff]);
      gload_lds16(Alp + ao, &AloS[loff]);
      gload_lds16(Bhp + bo, &BhiS[loff]);
      gload_lds16(Blp + bo, &BloS[loff]);
    }
    __syncthreads();
    bf16x8 fah[4], fal[4], fbh[4], fbl[4];
    #pragma unroll
    for (int i = 0; i < 4; ++i) {
      fah[i] = *(const bf16x8*)&AhiS[(wm + i * 16 + rr) * 32 + kq];
      fal[i] = *(const bf16x8*)&AloS[(wm + i * 16 + rr) * 32 + kq];
      fbh[i] = *(const bf16x8*)&BhiS[(wn + i * 16 + rr) * 32 + kq];
      fbl[i] = *(const bf16x8*)&BloS[(wn + i * 16 + rr) * 32 + kq];
    }
    #pragma unroll
    for (int mi = 0; mi < 4; ++mi)
      #pragma unroll
      for (int ni = 0; ni < 4; ++ni) {
        acc[mi][ni] = __builtin_amdgcn_mfma_f32_16x16x32_bf16(fah[mi], fbh[ni], acc[mi][ni], 0, 0, 0);
        acc[mi][ni] = __builtin_amdgcn_mfma_f32_16x16x32_bf16(fah[mi], fbl[ni], acc[mi][ni], 0, 0, 0);
        acc[mi][ni] = __builtin_amdgcn_mfma_f32_16x16x32_bf16(fal[mi], fbh[ni], acc[mi][ni], 0, 0, 0);
      }
    __syncthreads();
  }

  const int er = lane >> 4, ec = lane & 15;
  #pragma unroll
  for (int mi = 0; mi < 4; ++mi)
    #pragma unroll
    for (int ni = 0; ni < 4; ++ni) {
      const int gcol = n0 + wn + ni * 16 + ec;
      #pragma unroll
      for (int e = 0; e < 4; ++e) {
        const int grow = m0 + wm + mi * 16 + er * 4 + e;
        const long off = (long)z * sCz + (long)grow * ldc + gcol;
        if (OUTMODE == 0) {
          ((float*)C0)[off] = acc[mi][ni][e];
        } else {
          const float val = acc[mi][ni][e];
          const unsigned short hi = f2bf(val);
          ((unsigned short*)C0)[off] = hi;
          Clo[off] = f2bf(val - bf2f(hi));
        }
      }
    }
}

// ---------------- column softmax: row-softmax of sT[b][j][:], mask i>=j ----
__global__ __launch_bounds__(256)
void col_softmax(float* __restrict__ sT)
{
  const int T = 2048;
  const int j = blockIdx.x;
  float* row = sT + ((long)blockIdx.y * T + j) * T;
  const int tid = threadIdx.x;
  __shared__ float red[4];
  float lv[8];
  float lmax = -3.0e38f;
  #pragma unroll
  for (int p = 0; p < 2; ++p) {
    float4 v = *(const float4*)&row[tid * 4 + p * 1024];
    const int i0 = tid * 4 + p * 1024;
    lv[p * 4 + 0] = 32.f * v.x; if (i0 + 0 >= j) lmax = fmaxf(lmax, lv[p * 4 + 0]);
    lv[p * 4 + 1] = 32.f * v.y; if (i0 + 1 >= j) lmax = fmaxf(lmax, lv[p * 4 + 1]);
    lv[p * 4 + 2] = 32.f * v.z; if (i0 + 2 >= j) lmax = fmaxf(lmax, lv[p * 4 + 2]);
    lv[p * 4 + 3] = 32.f * v.w; if (i0 + 3 >= j) lmax = fmaxf(lmax, lv[p * 4 + 3]);
  }
  #pragma unroll
  for (int o = 32; o; o >>= 1) lmax = fmaxf(lmax, __shfl_down(lmax, o));
  if ((tid & 63) == 0) red[tid >> 6] = lmax;
  __syncthreads();
  const float m = fmaxf(fmaxf(red[0], red[1]), fmaxf(red[2], red[3]));
  __syncthreads();
  float zs = 0.f;
  #pragma unroll
  for (int p = 0; p < 2; ++p)
    #pragma unroll
    for (int q = 0; q < 4; ++q) {
      const int i = tid * 4 + p * 1024 + q;
      if (i >= j) zs += __expf(lv[p * 4 + q] - m);
    }
  #pragma unroll
  for (int o = 32; o; o >>= 1) zs += __shfl_down(zs, o);
  if ((tid & 63) == 0) red[tid >> 6] = zs;
  __syncthreads();
  const float rz = 1.f / (red[0] + red[1] + red[2] + red[3]);
  unsigned short* wrow = (unsigned short*)row;
  #pragma unroll
  for (int p = 0; p < 2; ++p) {
    ushort4 o;
    #pragma unroll
    for (int q = 0; q < 4; ++q) {
      const int i = tid * 4 + p * 1024 + q;
      const float wv = (i >= j) ? __expf(lv[p * 4 + q] - m) * rz : 0.f;
      ((unsigned short*)&o)[q] = f2bf(wv);
    }
    *(ushort4*)&wrow[tid * 4 + p * 1024] = o;
  }
}

// ---------------- 64x64 tiled bf16 transpose ----------------
__global__ __launch_bounds__(256)
void transpose_bf16(const unsigned short* __restrict__ in, unsigned short* __restrict__ out,
                    int ldin, int ldout, long sInZ, long sOutZ)
{
  __shared__ unsigned short tile[64][65];
  const int z = blockIdx.z;
  const int i0 = blockIdx.x * 64;
  const int j0 = blockIdx.y * 64;
  const int t = threadIdx.x;
  const int r = t >> 4;
  const int c = (t & 15) * 4;
  #pragma unroll
  for (int p = 0; p < 4; ++p) {
    const int row = j0 + r + p * 16;
    const unsigned short* ip = in + z * sInZ + (long)row * ldin + i0 + c;
    ushort4 v = *(const ushort4*)ip;
    tile[r + p * 16][c + 0] = v.x;
    tile[r + p * 16][c + 1] = v.y;
    tile[r + p * 16][c + 2] = v.z;
    tile[r + p * 16][c + 3] = v.w;
  }
  __syncthreads();
  #pragma unroll
  for (int p = 0; p < 4; ++p) {
    const int orow = i0 + r + p * 16;
    ushort4 o;
    o.x = tile[c + 0][r + p * 16];
    o.y = tile[c + 1][r + p * 16];
    o.z = tile[c + 2][r + p * 16];
    o.w = tile[c + 3][r + p * 16];
    *(ushort4*)&out[(long)z * sOutZ + (long)orow * ldout + j0 + c] = o;
  }
}

// ---------------- fp32 -> bf16 casts ----------------
__global__ __launch_bounds__(256)
void cast_f32_bf16(const float* __restrict__ in, unsigned short* __restrict__ out, int n4)
{
  const int i = blockIdx.x * 256 + threadIdx.x;
  if (i < n4) {
    float4 v = *(const float4*)&in[i * 4];
    ushort4 o; o.x = f2bf(v.x); o.y = f2bf(v.y); o.z = f2bf(v.z); o.w = f2bf(v.w);
    *(ushort4*)&out[i * 4] = o;
  }
}

__global__ __launch_bounds__(256)
void cast_f32_split(const float* __restrict__ in, unsigned short* __restrict__ hi,
                    unsigned short* __restrict__ lo, int n4)
{
  const int i = blockIdx.x * 256 + threadIdx.x;
  if (i < n4) {
    float4 v = *(const float4*)&in[i * 4];
    ushort4 h, l;
    h.x = f2bf(v.x); l.x = f2bf(v.x - bf2f(h.x));
    h.y = f2bf(v.y); l.y = f2bf(v.y - bf2f(h.y));
    h.z = f2bf(v.z); l.z = f2bf(v.z - bf2f(h.z));
    h.w = f2bf(v.w); l.w = f2bf(v.w - bf2f(h.w));
    *(ushort4*)&hi[i * 4] = h;
    *(ushort4*)&lo[i * 4] = l;
  }
}

// ============================================================================
extern "C" void kernel_launch(void* const* d_in, const int* in_sizes, int n_in,
                              void* d_out, int out_size, void* d_ws, size_t ws_size,
                              hipStream_t stream)
{
  (void)in_sizes; (void)n_in; (void)out_size; (void)ws_size;
  const int BT = 8192;           // B*T = 4*2048
  const long TT = 2048L * 2048;  // per-batch matrix elements

  const float* x   = (const float*)d_in[0];
  const float* Wk  = (const float*)d_in[1];
  const float* Wq  = (const float*)d_in[2];
  const float* Wv  = (const float*)d_in[3];
  const float* Wl  = (const float*)d_in[4];
  const float* bl  = (const float*)d_in[5];
  const float* W1  = (const float*)d_in[6];
  const float* b1  = (const float*)d_in[7];
  const float* W2  = (const float*)d_in[8];
  const float* b2  = (const float*)d_in[9];
  const float* g1  = (const float*)d_in[10];
  const float* be1 = (const float*)d_in[11];
  const float* g2  = (const float*)d_in[12];
  const float* be2 = (const float*)d_in[13];
  float* out = (float*)d_out;

  // ---- workspace layout (time-aliased, peak 224 MB) ----
  char* ws = (char*)d_ws;
  const size_t MB = 1024 * 1024;
  unsigned short* khi = (unsigned short*)(ws + 0);         // [8192][2048]
  unsigned short* klo = (unsigned short*)(ws + 32 * MB);
  unsigned short* qhi = (unsigned short*)(ws + 64 * MB);
  unsigned short* qlo = (unsigned short*)(ws + 96 * MB);
  unsigned short* hhi = (unsigned short*)(ws + 128 * MB);  // [8192][1024], dies before sT
  unsigned short* hlo = (unsigned short*)(ws + 144 * MB);
  unsigned short* Wkhi = (unsigned short*)(ws + 160 * MB); // weight splits, die before sT
  unsigned short* Wklo = (unsigned short*)(ws + 164 * MB);
  unsigned short* Wqhi = (unsigned short*)(ws + 168 * MB);
  unsigned short* Wqlo = (unsigned short*)(ws + 172 * MB);
  unsigned short* Wvb  = (unsigned short*)(ws + 176 * MB);
  float* sT = (float*)(ws + 128 * MB);                     // 4x[2048][2048] f32
  unsigned short* vT  = (unsigned short*)(ws + 192 * MB);  // [2048][8192]
  unsigned short* w   = (unsigned short*)(ws + 64 * MB);   // over dead qhi
  unsigned short* att = (unsigned short*)(ws + 96 * MB);   // over dead qlo
  unsigned short* Wlb = (unsigned short*)(ws + 0);         // over dead khi (post-scores)
  unsigned short* W1b = (unsigned short*)(ws + 4 * MB);
  unsigned short* W2b = (unsigned short*)(ws + 12 * MB);
  unsigned short* h2  = (unsigned short*)(ws + 20 * MB);   // over dead klo
  unsigned short* ff1 = (unsigned short*)(ws + 128 * MB);  // over dead sT

  // 1. LN1 -> split h ; weight splits/casts for the projection phase
  layernorm_k<2><<<dim3(BT), 256, 0, stream>>>(x, g1, be1, hhi, hlo);
  cast_f32_split<<<dim3(2048), 256, 0, stream>>>(Wk, Wkhi, Wklo, 2097152 / 4);
  cast_f32_split<<<dim3(2048), 256, 0, stream>>>(Wq, Wqhi, Wqlo, 2097152 / 4);
  cast_f32_bf16<<<dim3(2048), 256, 0, stream>>>(Wv, Wvb, 2097152 / 4);

  // 2. projections
  {
    dim3 g(2048 / 128, BT / 128, 1);  // (16, 64)
    gemm_split2<1><<<g, 256, 0, stream>>>(hhi, hlo, Wkhi, Wklo, (void*)khi, klo,
                                          1024, 1024, 1024, 2048, 0, 0, 0);
    gemm_split2<1><<<g, 256, 0, stream>>>(hhi, hlo, Wqhi, Wqlo, (void*)qhi, qlo,
                                          1024, 1024, 1024, 2048, 0, 0, 0);
    gemm_bt<1, 0, 0, 0, 1><<<g, 256, 0, stream>>>(hhi, Wvb, (void*)vT, nullptr, nullptr,
                                                  1024, 1024, 1024, 8192, 0, 0, 0);
  }

  // 3. sT[b][j][i] = dot(q_j, k_i)  (batched split GEMM, fp32 out)
  gemm_split2<0><<<dim3(16, 16, 4), 256, 0, stream>>>(qhi, qlo, khi, klo, (void*)sT, nullptr,
                                                      2048, 2048, 2048, 2048, TT, TT, TT);

  // 4. column softmax (mask i>=j), in-place bf16 wT
  col_softmax<<<dim3(2048, 4), 256, 0, stream>>>(sT);

  // 5. transpose wT -> w  (bf16 rows live in fp32-row storage: ld 4096)
  transpose_bf16<<<dim3(32, 32, 4), 256, 0, stream>>>((const unsigned short*)sT, w,
                                                      4096, 2048, 2048L * 4096, TT);

  // weight casts for the tail (khi/klo dead now)
  cast_f32_bf16<<<dim3(2048), 256, 0, stream>>>(Wl, Wlb, 2097152 / 4);
  cast_f32_bf16<<<dim3(4096), 256, 0, stream>>>(W1, W1b, 4194304 / 4);
  cast_f32_bf16<<<dim3(4096), 256, 0, stream>>>(W2, W2b, 4194304 / 4);

  // 6. att = w @ vT^T (batched; vT row d of batch z starts at d*8192 + z*2048)
  gemm_bt<1, 0, 0, 0, 0><<<dim3(16, 16, 4), 256, 0, stream>>>(w, vT, (void*)att, nullptr, nullptr,
                                                              2048, 2048, 8192, 2048, TT, 2048, TT);

  // 7. d_out = x + relu(att @ Wl^T + bl)
  gemm_bt<0, 1, 1, 1, 0><<<dim3(8, 64, 1), 256, 0, stream>>>(att, Wlb, (void*)out, bl, x,
                                                             2048, 2048, 2048, 1024, 0, 0, 0);

  // 8. LN2
  layernorm_k<1><<<dim3(BT), 256, 0, stream>>>(out, g2, be2, h2, nullptr);

  // 9. ff1 = relu(h2 @ W1^T + b1)
  gemm_bt<1, 1, 1, 0, 0><<<dim3(32, 64, 1), 256, 0, stream>>>(h2, W1b, (void*)ff1, b1, nullptr,
                                                              1024, 1024, 1024, 4096, 0, 0, 0);

  // 10. d_out += ff1 @ W2^T + b2
  gemm_bt<0, 1, 0, 1, 0><<<dim3(8, 64, 1), 256, 0, stream>>>(ff1, W2b, (void*)out, b2, out,
                                                             4096, 4096, 4096, 1024, 0, 0, 0);
}

// Round 4
// 926.790 us; speedup vs baseline: 1.2082x; 1.0461x over previous
//
#include <hip/hip_runtime.h>
#include <stdint.h>

// ============================================================================
// ScaledHeadBlock fused pipeline for MI355X (gfx950).
//
// Precision scheme: the k/q/scores path needs ~17 mantissa bits (logit std
// ~480, column-softmax is near-argmax). All high-precision values are stored
// as SPLIT bf16 (hi + lo), and GEMMs on them run 3 MFMAs per fragment pair
// (hh + hl + lh) on pre-split operands -- no in-loop conversion VALU work.
// Post-softmax path (v, att, FFN) is plain bf16.
//
// Causal-mask exploitation (this round):
//  - scores GEMM: compact triangular grid (136/256 blocks per batch);
//    masked blocks are never computed (softmax ignores that region).
//  - att GEMM: per-row-block K truncation, Kend = m0+128 (w[i][j]=0 for j>i
//    exactly, so truncation is exact).
//
//  1. LN1: x -> hhi,hlo (bf16 split);  Wk,Wq -> hi/lo; Wv -> bf16
//  2. khi/klo, qhi/qlo = split GEMMs; vT = (h @ Wv^T)^T (bf16, trans-out)
//  3. sT[b][j][i] = dot(q_j,k_i)  (split GEMM, triangular grid, fp32 out)
//  4. column softmax (mask i>=j), in-place bf16 wT
//  5. transpose wT -> w[i][j] bf16
//  6. att = w @ vT^T (bf16 GEMM, K-truncated)
//  7. d_out = x + relu(att @ Wl^T + bl)
//  8. LN2 -> h2 (bf16)
//  9. ff1 = relu(h2 @ W1^T + b1)
// 10. d_out += ff1 @ W2^T + b2
//
// Workspace (MB, peak 224):
//   khi[0,32) klo[32,64) qhi[64,96) qlo[96,128)
//   hhi[128,144) hlo[144,160) WkWqWv-splits[160,184)   } dead before sT
//   sT[128,192) fp32                                    } then ff1[128,192)
//   vT[192,224)
//   after scores: Wlb[0,4) W1b[4,12) W2b[12,20) h2[20,36)
//   w[64,96) att[96,128)
// ============================================================================

typedef __attribute__((ext_vector_type(8))) short bf16x8;
typedef __attribute__((ext_vector_type(4))) float floatx4;

#define DEVFN static __device__ __forceinline__

DEVFN unsigned short f2bf(float f) {
  union { float f; unsigned u; } v; v.f = f;
  return (unsigned short)((v.u + 0x7fffu + ((v.u >> 16) & 1u)) >> 16);
}
DEVFN float bf2f(unsigned short u) {
  union { unsigned u; float f; } v; v.u = ((unsigned)u) << 16; return v.f;
}
DEVFN void gload_lds16(const void* g, void* l) {
  __builtin_amdgcn_global_load_lds(
      (const __attribute__((address_space(1))) void*)g,
      (__attribute__((address_space(3))) void*)l, 16, 0, 0);
}

// ---------------- LayerNorm over rows of 1024 floats ----------------
// OUTMODE: 1 = single bf16, 2 = split hi/lo bf16
template<int OUTMODE>
__global__ __launch_bounds__(256)
void layernorm_k(const float* __restrict__ X, const float* __restrict__ g,
                 const float* __restrict__ be, unsigned short* __restrict__ o_hi,
                 unsigned short* __restrict__ o_lo)
{
  const int tid = threadIdx.x;
  const long base = (long)blockIdx.x * 1024 + tid * 4;
  __shared__ float red[4];
  float4 xv = *(const float4*)&X[base];
  float s = xv.x + xv.y + xv.z + xv.w;
  #pragma unroll
  for (int o = 32; o; o >>= 1) s += __shfl_down(s, o);
  if ((tid & 63) == 0) red[tid >> 6] = s;
  __syncthreads();
  const float mu = (red[0] + red[1] + red[2] + red[3]) * (1.f / 1024.f);
  __syncthreads();
  const float d0 = xv.x - mu, d1 = xv.y - mu, d2 = xv.z - mu, d3 = xv.w - mu;
  float ss = d0*d0 + d1*d1 + d2*d2 + d3*d3;
  #pragma unroll
  for (int o = 32; o; o >>= 1) ss += __shfl_down(ss, o);
  if ((tid & 63) == 0) red[tid >> 6] = ss;
  __syncthreads();
  const float var = (red[0] + red[1] + red[2] + red[3]) * (1.f / 1024.f);
  const float inv = rsqrtf(var + 1e-5f);
  float4 gv = *(const float4*)&g[tid * 4];
  float4 bv = *(const float4*)&be[tid * 4];
  float y[4];
  y[0] = d0 * inv * gv.x + bv.x;
  y[1] = d1 * inv * gv.y + bv.y;
  y[2] = d2 * inv * gv.z + bv.z;
  y[3] = d3 * inv * gv.w + bv.w;
  ushort4 hi, lo;
  #pragma unroll
  for (int e = 0; e < 4; ++e) {
    const unsigned short h = f2bf(y[e]);
    ((unsigned short*)&hi)[e] = h;
    if (OUTMODE == 2) ((unsigned short*)&lo)[e] = f2bf(y[e] - bf2f(h));
  }
  *(ushort4*)&o_hi[base] = hi;
  if (OUTMODE == 2) *(ushort4*)&o_lo[base] = lo;
}

// ---------------- bf16 BT-GEMM: C[m][n] = act(sum_k A[m][k]*B[n][k] + bias + res)
// 128x128 tile, BK=32, 256 threads (4 waves, 2x2 of 64x64), global_load_lds staging.
// TROUT=1: write bf16 C^T (C[n][m]) via ushort4, ignore BIAS/RELU/RES.
// KTRI=1: truncate reduction at m0+128 (valid when B-contribution is exactly
//         zero beyond the diagonal block, as for att = w @ vT).
template<int OUTBF, int BIAS, int RELU, int RES, int TROUT, int KTRI>
__global__ __launch_bounds__(256)
void gemm_bt(const unsigned short* __restrict__ A,
             const unsigned short* __restrict__ B,
             void* __restrict__ Cv,
             const float* __restrict__ bias,
             const float* __restrict__ res,
             int K, int lda, int ldb, int ldc,
             long sAz, long sBz, long sCz)
{
  __shared__ unsigned short As[128 * 32];
  __shared__ unsigned short Bs[128 * 32];
  const int z = blockIdx.z;
  const unsigned short* Ap = A + (long)z * sAz;
  const unsigned short* Bp = B + (long)z * sBz;
  const int m0 = blockIdx.y * 128, n0 = blockIdx.x * 128;
  const int tid = threadIdx.x, lane = tid & 63, wave = tid >> 6;
  const int wm = (wave >> 1) * 64, wn = (wave & 1) * 64;
  const int crow = lane >> 2;          // row within 16-row chunk
  const int ccol = (lane & 3) * 8;     // col (elements) within 32-wide row
  const int kq = (lane >> 4) * 8, rr = lane & 15;

  const int Kend = KTRI ? min(K, m0 + 128) : K;

  floatx4 acc[4][4];
  #pragma unroll
  for (int i = 0; i < 4; ++i)
    #pragma unroll
    for (int j = 0; j < 4; ++j) {
      acc[i][j][0] = 0.f; acc[i][j][1] = 0.f; acc[i][j][2] = 0.f; acc[i][j][3] = 0.f;
    }

  for (int k0 = 0; k0 < Kend; k0 += 32) {
    #pragma unroll
    for (int c = 0; c < 2; ++c) {
      const int chunk = wave + c * 4;            // wave-uniform
      const int row = chunk * 16 + crow;
      gload_lds16(Ap + (long)(m0 + row) * lda + k0 + ccol, &As[chunk * 512]);
      gload_lds16(Bp + (long)(n0 + row) * ldb + k0 + ccol, &Bs[chunk * 512]);
    }
    __syncthreads();
    bf16x8 af[4], bfr[4];
    #pragma unroll
    for (int i = 0; i < 4; ++i) {
      af[i]  = *(const bf16x8*)&As[(wm + i * 16 + rr) * 32 + kq];
      bfr[i] = *(const bf16x8*)&Bs[(wn + i * 16 + rr) * 32 + kq];
    }
    #pragma unroll
    for (int mi = 0; mi < 4; ++mi)
      #pragma unroll
      for (int ni = 0; ni < 4; ++ni)
        acc[mi][ni] = __builtin_amdgcn_mfma_f32_16x16x32_bf16(af[mi], bfr[ni], acc[mi][ni], 0, 0, 0);
    __syncthreads();
  }

  const int er = lane >> 4, ec = lane & 15;
  #pragma unroll
  for (int mi = 0; mi < 4; ++mi)
    #pragma unroll
    for (int ni = 0; ni < 4; ++ni) {
      const int gcol = n0 + wn + ni * 16 + ec;
      if (TROUT) {
        const int grow0 = m0 + wm + mi * 16 + er * 4;
        ushort4 o;
        o.x = f2bf(acc[mi][ni][0]); o.y = f2bf(acc[mi][ni][1]);
        o.z = f2bf(acc[mi][ni][2]); o.w = f2bf(acc[mi][ni][3]);
        *(ushort4*)&((unsigned short*)Cv)[(long)z * sCz + (long)gcol * ldc + grow0] = o;
      } else {
        const float bv = BIAS ? bias[gcol] : 0.f;
        #pragma unroll
        for (int e = 0; e < 4; ++e) {
          const int grow = m0 + wm + mi * 16 + er * 4 + e;
          const long off = (long)z * sCz + (long)grow * ldc + gcol;
          float val = acc[mi][ni][e] + bv;
          if (RELU) val = fmaxf(val, 0.f);
          if (RES) val += res[off];
          if (OUTBF) ((unsigned short*)Cv)[off] = f2bf(val);
          else       ((float*)Cv)[off] = val;
        }
      }
    }
}

// ---------------- split-bf16 BT-GEMM on PRE-SPLIT operands ----------------
// C = (Ahi+Alo) @ (Bhi+Blo)^T via 3 MFMAs/pair (hh + hl + lh), all staging
// through global_load_lds (no VALU conversions in the loop).
// OUTMODE 0: fp32 C.  OUTMODE 1: split bf16 Chi/Clo.
// TRIG=1: blockIdx.x in [0,136) decodes to upper-triangular (bm,bn), bn>=bm
//         (for scores sT[j][i]: only blocks with some i>=j are computed).
template<int OUTMODE, int TRIG>
__global__ __launch_bounds__(256)
void gemm_split2(const unsigned short* __restrict__ Ahi, const unsigned short* __restrict__ Alo,
                 const unsigned short* __restrict__ Bhi, const unsigned short* __restrict__ Blo,
                 void* __restrict__ C0, unsigned short* __restrict__ Clo,
                 int K, int lda, int ldb, int ldc,
                 long sAz, long sBz, long sCz)
{
  __shared__ unsigned short AhiS[128 * 32];
  __shared__ unsigned short AloS[128 * 32];
  __shared__ unsigned short BhiS[128 * 32];
  __shared__ unsigned short BloS[128 * 32];
  const int z = blockIdx.z;
  const unsigned short* Ahp = Ahi + (long)z * sAz;
  const unsigned short* Alp = Alo + (long)z * sAz;
  const unsigned short* Bhp = Bhi + (long)z * sBz;
  const unsigned short* Blp = Blo + (long)z * sBz;

  int bm, bn;
  if (TRIG) {
    int t = blockIdx.x, bj = 0;
    while (t >= 16 - bj) { t -= 16 - bj; ++bj; }
    bm = bj; bn = bj + t;          // bn >= bm
  } else {
    bm = blockIdx.y; bn = blockIdx.x;
  }
  const int m0 = bm * 128, n0 = bn * 128;
  const int tid = threadIdx.x, lane = tid & 63, wave = tid >> 6;
  const int wm = (wave >> 1) * 64, wn = (wave & 1) * 64;
  const int crow = lane >> 2;
  const int ccol = (lane & 3) * 8;
  const int kq = (lane >> 4) * 8, rr = lane & 15;

  floatx4 acc[4][4];
  #pragma unroll
  for (int i = 0; i < 4; ++i)
    #pragma unroll
    for (int j = 0; j < 4; ++j) {
      acc[i][j][0] = 0.f; acc[i][j][1] = 0.f; acc[i][j][2] = 0.f; acc[i][j][3] = 0.f;
    }

  for (int k0 = 0; k0 < K; k0 += 32) {
    #pragma unroll
    for (int c = 0; c < 2; ++c) {
      const int chunk = wave + c * 4;            // wave-uniform
      const int row = chunk * 16 + crow;
      const int loff = chunk * 512;
      const long ao = (long)(m0 + row) * lda + k0 + ccol;
      const long bo = (long)(n0 + row) * ldb + k0 + ccol;
      gload_lds16(Ahp + ao, &AhiS[loff]);
      gload_lds16(Alp + ao, &AloS[loff]);
      gload_lds16(Bhp + bo, &BhiS[loff]);
      gload_lds16(Blp + bo, &BloS[loff]);
    }
    __syncthreads();
    bf16x8 fah[4], fal[4], fbh[4], fbl[4];
    #pragma unroll
    for (int i = 0; i < 4; ++i) {
      fah[i] = *(const bf16x8*)&AhiS[(wm + i * 16 + rr) * 32 + kq];
      fal[i] = *(const bf16x8*)&AloS[(wm + i * 16 + rr) * 32 + kq];
      fbh[i] = *(const bf16x8*)&BhiS[(wn + i * 16 + rr) * 32 + kq];
      fbl[i] = *(const bf16x8*)&BloS[(wn + i * 16 + rr) * 32 + kq];
    }
    #pragma unroll
    for (int mi = 0; mi < 4; ++mi)
      #pragma unroll
      for (int ni = 0; ni < 4; ++ni) {
        acc[mi][ni] = __builtin_amdgcn_mfma_f32_16x16x32_bf16(fah[mi], fbh[ni], acc[mi][ni], 0, 0, 0);
        acc[mi][ni] = __builtin_amdgcn_mfma_f32_16x16x32_bf16(fah[mi], fbl[ni], acc[mi][ni], 0, 0, 0);
        acc[mi][ni] = __builtin_amdgcn_mfma_f32_16x16x32_bf16(fal[mi], fbh[ni], acc[mi][ni], 0, 0, 0);
      }
    __syncthreads();
  }

  const int er = lane >> 4, ec = lane & 15;
  #pragma unroll
  for (int mi = 0; mi < 4; ++mi)
    #pragma unroll
    for (int ni = 0; ni < 4; ++ni) {
      const int gcol = n0 + wn + ni * 16 + ec;
      #pragma unroll
      for (int e = 0; e < 4; ++e) {
        const int grow = m0 + wm + mi * 16 + er * 4 + e;
        const long off = (long)z * sCz + (long)grow * ldc + gcol;
        if (OUTMODE == 0) {
          ((float*)C0)[off] = acc[mi][ni][e];
        } else {
          const float val = acc[mi][ni][e];
          const unsigned short hi = f2bf(val);
          ((unsigned short*)C0)[off] = hi;
          Clo[off] = f2bf(val - bf2f(hi));
        }
      }
    }
}

// ---------------- column softmax: row-softmax of sT[b][j][:], mask i>=j ----
__global__ __launch_bounds__(256)
void col_softmax(float* __restrict__ sT)
{
  const int T = 2048;
  const int j = blockIdx.x;
  float* row = sT + ((long)blockIdx.y * T + j) * T;
  const int tid = threadIdx.x;
  __shared__ float red[4];
  float lv[8];
  float lmax = -3.0e38f;
  #pragma unroll
  for (int p = 0; p < 2; ++p) {
    float4 v = *(const float4*)&row[tid * 4 + p * 1024];
    const int i0 = tid * 4 + p * 1024;
    lv[p * 4 + 0] = 32.f * v.x; if (i0 + 0 >= j) lmax = fmaxf(lmax, lv[p * 4 + 0]);
    lv[p * 4 + 1] = 32.f * v.y; if (i0 + 1 >= j) lmax = fmaxf(lmax, lv[p * 4 + 1]);
    lv[p * 4 + 2] = 32.f * v.z; if (i0 + 2 >= j) lmax = fmaxf(lmax, lv[p * 4 + 2]);
    lv[p * 4 + 3] = 32.f * v.w; if (i0 + 3 >= j) lmax = fmaxf(lmax, lv[p * 4 + 3]);
  }
  #pragma unroll
  for (int o = 32; o; o >>= 1) lmax = fmaxf(lmax, __shfl_down(lmax, o));
  if ((tid & 63) == 0) red[tid >> 6] = lmax;
  __syncthreads();
  const float m = fmaxf(fmaxf(red[0], red[1]), fmaxf(red[2], red[3]));
  __syncthreads();
  float zs = 0.f;
  #pragma unroll
  for (int p = 0; p < 2; ++p)
    #pragma unroll
    for (int q = 0; q < 4; ++q) {
      const int i = tid * 4 + p * 1024 + q;
      if (i >= j) zs += __expf(lv[p * 4 + q] - m);
    }
  #pragma unroll
  for (int o = 32; o; o >>= 1) zs += __shfl_down(zs, o);
  if ((tid & 63) == 0) red[tid >> 6] = zs;
  __syncthreads();
  const float rz = 1.f / (red[0] + red[1] + red[2] + red[3]);
  unsigned short* wrow = (unsigned short*)row;
  #pragma unroll
  for (int p = 0; p < 2; ++p) {
    ushort4 o;
    #pragma unroll
    for (int q = 0; q < 4; ++q) {
      const int i = tid * 4 + p * 1024 + q;
      const float wv = (i >= j) ? __expf(lv[p * 4 + q] - m) * rz : 0.f;
      ((unsigned short*)&o)[q] = f2bf(wv);
    }
    *(ushort4*)&wrow[tid * 4 + p * 1024] = o;
  }
}

// ---------------- 64x64 tiled bf16 transpose ----------------
__global__ __launch_bounds__(256)
void transpose_bf16(const unsigned short* __restrict__ in, unsigned short* __restrict__ out,
                    int ldin, int ldout, long sInZ, long sOutZ)
{
  __shared__ unsigned short tile[64][65];
  const int z = blockIdx.z;
  const int i0 = blockIdx.x * 64;
  const int j0 = blockIdx.y * 64;
  const int t = threadIdx.x;
  const int r = t >> 4;
  const int c = (t & 15) * 4;
  #pragma unroll
  for (int p = 0; p < 4; ++p) {
    const int row = j0 + r + p * 16;
    const unsigned short* ip = in + z * sInZ + (long)row * ldin + i0 + c;
    ushort4 v = *(const ushort4*)ip;
    tile[r + p * 16][c + 0] = v.x;
    tile[r + p * 16][c + 1] = v.y;
    tile[r + p * 16][c + 2] = v.z;
    tile[r + p * 16][c + 3] = v.w;
  }
  __syncthreads();
  #pragma unroll
  for (int p = 0; p < 4; ++p) {
    const int orow = i0 + r + p * 16;
    ushort4 o;
    o.x = tile[c + 0][r + p * 16];
    o.y = tile[c + 1][r + p * 16];
    o.z = tile[c + 2][r + p * 16];
    o.w = tile[c + 3][r + p * 16];
    *(ushort4*)&out[(long)z * sOutZ + (long)orow * ldout + j0 + c] = o;
  }
}

// ---------------- fp32 -> bf16 casts ----------------
__global__ __launch_bounds__(256)
void cast_f32_bf16(const float* __restrict__ in, unsigned short* __restrict__ out, int n4)
{
  const int i = blockIdx.x * 256 + threadIdx.x;
  if (i < n4) {
    float4 v = *(const float4*)&in[i * 4];
    ushort4 o; o.x = f2bf(v.x); o.y = f2bf(v.y); o.z = f2bf(v.z); o.w = f2bf(v.w);
    *(ushort4*)&out[i * 4] = o;
  }
}

__global__ __launch_bounds__(256)
void cast_f32_split(const float* __restrict__ in, unsigned short* __restrict__ hi,
                    unsigned short* __restrict__ lo, int n4)
{
  const int i = blockIdx.x * 256 + threadIdx.x;
  if (i < n4) {
    float4 v = *(const float4*)&in[i * 4];
    ushort4 h, l;
    h.x = f2bf(v.x); l.x = f2bf(v.x - bf2f(h.x));
    h.y = f2bf(v.y); l.y = f2bf(v.y - bf2f(h.y));
    h.z = f2bf(v.z); l.z = f2bf(v.z - bf2f(h.z));
    h.w = f2bf(v.w); l.w = f2bf(v.w - bf2f(h.w));
    *(ushort4*)&hi[i * 4] = h;
    *(ushort4*)&lo[i * 4] = l;
  }
}

// ============================================================================
extern "C" void kernel_launch(void* const* d_in, const int* in_sizes, int n_in,
                              void* d_out, int out_size, void* d_ws, size_t ws_size,
                              hipStream_t stream)
{
  (void)in_sizes; (void)n_in; (void)out_size; (void)ws_size;
  const int BT = 8192;           // B*T = 4*2048
  const long TT = 2048L * 2048;  // per-batch matrix elements

  const float* x   = (const float*)d_in[0];
  const float* Wk  = (const float*)d_in[1];
  const float* Wq  = (const float*)d_in[2];
  const float* Wv  = (const float*)d_in[3];
  const float* Wl  = (const float*)d_in[4];
  const float* bl  = (const float*)d_in[5];
  const float* W1  = (const float*)d_in[6];
  const float* b1  = (const float*)d_in[7];
  const float* W2  = (const float*)d_in[8];
  const float* b2  = (const float*)d_in[9];
  const float* g1  = (const float*)d_in[10];
  const float* be1 = (const float*)d_in[11];
  const float* g2  = (const float*)d_in[12];
  const float* be2 = (const float*)d_in[13];
  float* out = (float*)d_out;

  // ---- workspace layout (time-aliased, peak 224 MB) ----
  char* ws = (char*)d_ws;
  const size_t MB = 1024 * 1024;
  unsigned short* khi = (unsigned short*)(ws + 0);         // [8192][2048]
  unsigned short* klo = (unsigned short*)(ws + 32 * MB);
  unsigned short* qhi = (unsigned short*)(ws + 64 * MB);
  unsigned short* qlo = (unsigned short*)(ws + 96 * MB);
  unsigned short* hhi = (unsigned short*)(ws + 128 * MB);  // [8192][1024], dies before sT
  unsigned short* hlo = (unsigned short*)(ws + 144 * MB);
  unsigned short* Wkhi = (unsigned short*)(ws + 160 * MB); // weight splits, die before sT
  unsigned short* Wklo = (unsigned short*)(ws + 164 * MB);
  unsigned short* Wqhi = (unsigned short*)(ws + 168 * MB);
  unsigned short* Wqlo = (unsigned short*)(ws + 172 * MB);
  unsigned short* Wvb  = (unsigned short*)(ws + 176 * MB);
  float* sT = (float*)(ws + 128 * MB);                     // 4x[2048][2048] f32
  unsigned short* vT  = (unsigned short*)(ws + 192 * MB);  // [2048][8192]
  unsigned short* w   = (unsigned short*)(ws + 64 * MB);   // over dead qhi
  unsigned short* att = (unsigned short*)(ws + 96 * MB);   // over dead qlo
  unsigned short* Wlb = (unsigned short*)(ws + 0);         // over dead khi (post-scores)
  unsigned short* W1b = (unsigned short*)(ws + 4 * MB);
  unsigned short* W2b = (unsigned short*)(ws + 12 * MB);
  unsigned short* h2  = (unsigned short*)(ws + 20 * MB);   // over dead klo
  unsigned short* ff1 = (unsigned short*)(ws + 128 * MB);  // over dead sT

  // 1. LN1 -> split h ; weight splits/casts for the projection phase
  layernorm_k<2><<<dim3(BT), 256, 0, stream>>>(x, g1, be1, hhi, hlo);
  cast_f32_split<<<dim3(2048), 256, 0, stream>>>(Wk, Wkhi, Wklo, 2097152 / 4);
  cast_f32_split<<<dim3(2048), 256, 0, stream>>>(Wq, Wqhi, Wqlo, 2097152 / 4);
  cast_f32_bf16<<<dim3(2048), 256, 0, stream>>>(Wv, Wvb, 2097152 / 4);

  // 2. projections
  {
    dim3 g(2048 / 128, BT / 128, 1);  // (16, 64)
    gemm_split2<1, 0><<<g, 256, 0, stream>>>(hhi, hlo, Wkhi, Wklo, (void*)khi, klo,
                                             1024, 1024, 1024, 2048, 0, 0, 0);
    gemm_split2<1, 0><<<g, 256, 0, stream>>>(hhi, hlo, Wqhi, Wqlo, (void*)qhi, qlo,
                                             1024, 1024, 1024, 2048, 0, 0, 0);
    gemm_bt<1, 0, 0, 0, 1, 0><<<g, 256, 0, stream>>>(hhi, Wvb, (void*)vT, nullptr, nullptr,
                                                     1024, 1024, 1024, 8192, 0, 0, 0);
  }

  // 3. sT[b][j][i] = dot(q_j, k_i)  (triangular block grid: 136 of 256)
  gemm_split2<0, 1><<<dim3(136, 1, 4), 256, 0, stream>>>(qhi, qlo, khi, klo, (void*)sT, nullptr,
                                                         2048, 2048, 2048, 2048, TT, TT, TT);

  // 4. column softmax (mask i>=j), in-place bf16 wT (masked region writes 0)
  col_softmax<<<dim3(2048, 4), 256, 0, stream>>>(sT);

  // 5. transpose wT -> w  (bf16 rows live in fp32-row storage: ld 4096)
  transpose_bf16<<<dim3(32, 32, 4), 256, 0, stream>>>((const unsigned short*)sT, w,
                                                      4096, 2048, 2048L * 4096, TT);

  // weight casts for the tail (khi/klo dead now)
  cast_f32_bf16<<<dim3(2048), 256, 0, stream>>>(Wl, Wlb, 2097152 / 4);
  cast_f32_bf16<<<dim3(4096), 256, 0, stream>>>(W1, W1b, 4194304 / 4);
  cast_f32_bf16<<<dim3(4096), 256, 0, stream>>>(W2, W2b, 4194304 / 4);

  // 6. att = w @ vT^T (batched, K truncated at the causal diagonal)
  gemm_bt<1, 0, 0, 0, 0, 1><<<dim3(16, 16, 4), 256, 0, stream>>>(w, vT, (void*)att, nullptr, nullptr,
                                                                 2048, 2048, 8192, 2048, TT, 2048, TT);

  // 7. d_out = x + relu(att @ Wl^T + bl)
  gemm_bt<0, 1, 1, 1, 0, 0><<<dim3(8, 64, 1), 256, 0, stream>>>(att, Wlb, (void*)out, bl, x,
                                                                2048, 2048, 2048, 1024, 0, 0, 0);

  // 8. LN2
  layernorm_k<1><<<dim3(BT), 256, 0, stream>>>(out, g2, be2, h2, nullptr);

  // 9. ff1 = relu(h2 @ W1^T + b1)
  gemm_bt<1, 1, 1, 0, 0, 0><<<dim3(32, 64, 1), 256, 0, stream>>>(h2, W1b, (void*)ff1, b1, nullptr,
                                                                 1024, 1024, 1024, 4096, 0, 0, 0);

  // 10. d_out += ff1 @ W2^T + b2
  gemm_bt<0, 1, 0, 1, 0, 0><<<dim3(8, 64, 1), 256, 0, stream>>>(ff1, W2b, (void*)out, b2, out,
                                                                4096, 4096, 4096, 1024, 0, 0, 0);
}

// Round 5
// 743.893 us; speedup vs baseline: 1.5052x; 1.2459x over previous
//
#include <hip/hip_runtime.h>
#include <stdint.h>

// ============================================================================
// ScaledHeadBlock fused pipeline for MI355X (gfx950).
//
// Key algebraic restructure: scores are computed WITHOUT materializing k,q:
//   w[i][j] = k_i . q_j = h_i . M . h_j^T,  M[c1][c2] = sum_d Wk[d][c1] Wq[d][c2]
// So:  MT = WqT @ WkT^T   (1024x1024, K=2048)     [split, K-split x8, atomic]
//      G  = h @ MT^T... G[i][c2] = sum_c1 h[i][c1] MT[c2][c1]  (8192x1024,K=1024)
//      sT[j][i] = sum_c h[j][c] G[i][c]   (triangular, K=1024, K-split x2)
// This is 3.5x fewer split-GEMM FLOPs than k/q projections + k.q^T scores.
//
// Precision: high-precision operands stored as SPLIT bf16 (hi+lo, ~17 bits),
// GEMMs run 3 MFMAs per fragment pair (hh+hl+lh). fp32 accumulation via
// atomicAdd partials (commutative). Post-softmax path is plain bf16.
//
// Workspace (MB, peak 192):
//   hhi[0,16) hlo[16,32) vT[32,64)
//   WqT-split[64,72) WkT-split[72,80) MTf32[80,84) MT-split[84,88) Wvb[88,92)
//   G-split[96,128)  Gf32[160,192)  sT[128,192) fp32
//   post-scores: Wlb[0,4) W1b[4,12) W2b[12,20) h2[20,36) w[64,96) att[96,128)
//   ff1[128,192)
// ============================================================================

typedef __attribute__((ext_vector_type(8))) short bf16x8;
typedef __attribute__((ext_vector_type(4))) float floatx4;

#define DEVFN static __device__ __forceinline__

DEVFN unsigned short f2bf(float f) {
  union { float f; unsigned u; } v; v.f = f;
  return (unsigned short)((v.u + 0x7fffu + ((v.u >> 16) & 1u)) >> 16);
}
DEVFN float bf2f(unsigned short u) {
  union { unsigned u; float f; } v; v.u = ((unsigned)u) << 16; return v.f;
}
DEVFN void gload_lds16(const void* g, void* l) {
  __builtin_amdgcn_global_load_lds(
      (const __attribute__((address_space(1))) void*)g,
      (__attribute__((address_space(3))) void*)l, 16, 0, 0);
}

// ---------------- zero fill (graph-capture-safe memset) ----------------
__global__ __launch_bounds__(256)
void zero_f32(float* __restrict__ p, int n4)
{
  const int i = blockIdx.x * 256 + threadIdx.x;
  if (i < n4) {
    float4 z; z.x = 0.f; z.y = 0.f; z.z = 0.f; z.w = 0.f;
    *(float4*)&p[i * 4] = z;
  }
}

// ---------------- LayerNorm over rows of 1024 floats ----------------
// OUTMODE: 1 = single bf16, 2 = split hi/lo bf16
template<int OUTMODE>
__global__ __launch_bounds__(256)
void layernorm_k(const float* __restrict__ X, const float* __restrict__ g,
                 const float* __restrict__ be, unsigned short* __restrict__ o_hi,
                 unsigned short* __restrict__ o_lo)
{
  const int tid = threadIdx.x;
  const long base = (long)blockIdx.x * 1024 + tid * 4;
  __shared__ float red[4];
  float4 xv = *(const float4*)&X[base];
  float s = xv.x + xv.y + xv.z + xv.w;
  #pragma unroll
  for (int o = 32; o; o >>= 1) s += __shfl_down(s, o);
  if ((tid & 63) == 0) red[tid >> 6] = s;
  __syncthreads();
  const float mu = (red[0] + red[1] + red[2] + red[3]) * (1.f / 1024.f);
  __syncthreads();
  const float d0 = xv.x - mu, d1 = xv.y - mu, d2 = xv.z - mu, d3 = xv.w - mu;
  float ss = d0*d0 + d1*d1 + d2*d2 + d3*d3;
  #pragma unroll
  for (int o = 32; o; o >>= 1) ss += __shfl_down(ss, o);
  if ((tid & 63) == 0) red[tid >> 6] = ss;
  __syncthreads();
  const float var = (red[0] + red[1] + red[2] + red[3]) * (1.f / 1024.f);
  const float inv = rsqrtf(var + 1e-5f);
  float4 gv = *(const float4*)&g[tid * 4];
  float4 bv = *(const float4*)&be[tid * 4];
  float y[4];
  y[0] = d0 * inv * gv.x + bv.x;
  y[1] = d1 * inv * gv.y + bv.y;
  y[2] = d2 * inv * gv.z + bv.z;
  y[3] = d3 * inv * gv.w + bv.w;
  ushort4 hi, lo;
  #pragma unroll
  for (int e = 0; e < 4; ++e) {
    const unsigned short h = f2bf(y[e]);
    ((unsigned short*)&hi)[e] = h;
    if (OUTMODE == 2) ((unsigned short*)&lo)[e] = f2bf(y[e] - bf2f(h));
  }
  *(ushort4*)&o_hi[base] = hi;
  if (OUTMODE == 2) *(ushort4*)&o_lo[base] = lo;
}

// ---------------- bf16 BT-GEMM: C[m][n] = act(sum_k A[m][k]*B[n][k] + bias + res)
// 128x128 tile, BK=32, 256 threads (4 waves, 2x2 of 64x64), global_load_lds staging.
// TROUT=1: write bf16 C^T (C[n][m]) via ushort4, ignore BIAS/RELU/RES.
// KTRI=1: truncate reduction at m0+128 (valid when B-cols beyond diag are 0).
template<int OUTBF, int BIAS, int RELU, int RES, int TROUT, int KTRI>
__global__ __launch_bounds__(256)
void gemm_bt(const unsigned short* __restrict__ A,
             const unsigned short* __restrict__ B,
             void* __restrict__ Cv,
             const float* __restrict__ bias,
             const float* __restrict__ res,
             int K, int lda, int ldb, int ldc,
             long sAz, long sBz, long sCz)
{
  __shared__ unsigned short As[128 * 32];
  __shared__ unsigned short Bs[128 * 32];
  const int z = blockIdx.z;
  const unsigned short* Ap = A + (long)z * sAz;
  const unsigned short* Bp = B + (long)z * sBz;
  const int m0 = blockIdx.y * 128, n0 = blockIdx.x * 128;
  const int tid = threadIdx.x, lane = tid & 63, wave = tid >> 6;
  const int wm = (wave >> 1) * 64, wn = (wave & 1) * 64;
  const int crow = lane >> 2;          // row within 16-row chunk
  const int ccol = (lane & 3) * 8;     // col (elements) within 32-wide row
  const int kq = (lane >> 4) * 8, rr = lane & 15;

  const int Kend = KTRI ? min(K, m0 + 128) : K;

  floatx4 acc[4][4];
  #pragma unroll
  for (int i = 0; i < 4; ++i)
    #pragma unroll
    for (int j = 0; j < 4; ++j) {
      acc[i][j][0] = 0.f; acc[i][j][1] = 0.f; acc[i][j][2] = 0.f; acc[i][j][3] = 0.f;
    }

  for (int k0 = 0; k0 < Kend; k0 += 32) {
    #pragma unroll
    for (int c = 0; c < 2; ++c) {
      const int chunk = wave + c * 4;            // wave-uniform
      const int row = chunk * 16 + crow;
      gload_lds16(Ap + (long)(m0 + row) * lda + k0 + ccol, &As[chunk * 512]);
      gload_lds16(Bp + (long)(n0 + row) * ldb + k0 + ccol, &Bs[chunk * 512]);
    }
    __syncthreads();
    bf16x8 af[4], bfr[4];
    #pragma unroll
    for (int i = 0; i < 4; ++i) {
      af[i]  = *(const bf16x8*)&As[(wm + i * 16 + rr) * 32 + kq];
      bfr[i] = *(const bf16x8*)&Bs[(wn + i * 16 + rr) * 32 + kq];
    }
    #pragma unroll
    for (int mi = 0; mi < 4; ++mi)
      #pragma unroll
      for (int ni = 0; ni < 4; ++ni)
        acc[mi][ni] = __builtin_amdgcn_mfma_f32_16x16x32_bf16(af[mi], bfr[ni], acc[mi][ni], 0, 0, 0);
    __syncthreads();
  }

  const int er = lane >> 4, ec = lane & 15;
  #pragma unroll
  for (int mi = 0; mi < 4; ++mi)
    #pragma unroll
    for (int ni = 0; ni < 4; ++ni) {
      const int gcol = n0 + wn + ni * 16 + ec;
      if (TROUT) {
        const int grow0 = m0 + wm + mi * 16 + er * 4;
        ushort4 o;
        o.x = f2bf(acc[mi][ni][0]); o.y = f2bf(acc[mi][ni][1]);
        o.z = f2bf(acc[mi][ni][2]); o.w = f2bf(acc[mi][ni][3]);
        *(ushort4*)&((unsigned short*)Cv)[(long)z * sCz + (long)gcol * ldc + grow0] = o;
      } else {
        const float bv = BIAS ? bias[gcol] : 0.f;
        #pragma unroll
        for (int e = 0; e < 4; ++e) {
          const int grow = m0 + wm + mi * 16 + er * 4 + e;
          const long off = (long)z * sCz + (long)grow * ldc + gcol;
          float val = acc[mi][ni][e] + bv;
          if (RELU) val = fmaxf(val, 0.f);
          if (RES) val += res[off];
          if (OUTBF) ((unsigned short*)Cv)[off] = f2bf(val);
          else       ((float*)Cv)[off] = val;
        }
      }
    }
}

// ---------------- split-bf16 BT-GEMM on PRE-SPLIT operands ----------------
// C(fp32) += (Ahi+Alo) @ (Bhi+Blo)^T via 3 MFMAs/pair (hh + hl + lh).
// Runtime K-split (nks blocks per tile, each does K/nks) with fp32 atomicAdd
// epilogue into a pre-zeroed buffer (2-way adds are exactly commutative).
// TRIG=1: tile index decodes to upper-triangular (bm,bn), bn>=bm, 16x16 tiles.
template<int TRIG>
__global__ __launch_bounds__(256)
void gemm_split2(const unsigned short* __restrict__ Ahi, const unsigned short* __restrict__ Alo,
                 const unsigned short* __restrict__ Bhi, const unsigned short* __restrict__ Blo,
                 float* __restrict__ C,
                 int K, int nks, int lda, int ldb, int ldc,
                 long sAz, long sBz, long sCz)
{
  __shared__ unsigned short AhiS[128 * 32];
  __shared__ unsigned short AloS[128 * 32];
  __shared__ unsigned short BhiS[128 * 32];
  __shared__ unsigned short BloS[128 * 32];
  const int z = blockIdx.z;
  const unsigned short* Ahp = Ahi + (long)z * sAz;
  const unsigned short* Alp = Alo + (long)z * sAz;
  const unsigned short* Bhp = Bhi + (long)z * sBz;
  const unsigned short* Blp = Blo + (long)z * sBz;

  int bm, bn, ks;
  if (TRIG) {
    int xx = blockIdx.x;
    ks = xx % nks;
    int t = xx / nks, bj = 0;
    while (t >= 16 - bj) { t -= 16 - bj; ++bj; }
    bm = bj; bn = bj + t;          // bn >= bm
  } else {
    ks = blockIdx.x % nks;
    bn = blockIdx.x / nks;
    bm = blockIdx.y;
  }
  const int kper = K / nks;
  const int kbeg = ks * kper, kstop = kbeg + kper;

  const int m0 = bm * 128, n0 = bn * 128;
  const int tid = threadIdx.x, lane = tid & 63, wave = tid >> 6;
  const int wm = (wave >> 1) * 64, wn = (wave & 1) * 64;
  const int crow = lane >> 2;
  const int ccol = (lane & 3) * 8;
  const int kq = (lane >> 4) * 8, rr = lane & 15;

  floatx4 acc[4][4];
  #pragma unroll
  for (int i = 0; i < 4; ++i)
    #pragma unroll
    for (int j = 0; j < 4; ++j) {
      acc[i][j][0] = 0.f; acc[i][j][1] = 0.f; acc[i][j][2] = 0.f; acc[i][j][3] = 0.f;
    }

  for (int k0 = kbeg; k0 < kstop; k0 += 32) {
    #pragma unroll
    for (int c = 0; c < 2; ++c) {
      const int chunk = wave + c * 4;            // wave-uniform
      const int row = chunk * 16 + crow;
      const int loff = chunk * 512;
      const long ao = (long)(m0 + row) * lda + k0 + ccol;
      const long bo = (long)(n0 + row) * ldb + k0 + ccol;
      gload_lds16(Ahp + ao, &AhiS[loff]);
      gload_lds16(Alp + ao, &AloS[loff]);
      gload_lds16(Bhp + bo, &BhiS[loff]);
      gload_lds16(Blp + bo, &BloS[loff]);
    }
    __syncthreads();
    bf16x8 fah[4], fal[4], fbh[4], fbl[4];
    #pragma unroll
    for (int i = 0; i < 4; ++i) {
      fah[i] = *(const bf16x8*)&AhiS[(wm + i * 16 + rr) * 32 + kq];
      fal[i] = *(const bf16x8*)&AloS[(wm + i * 16 + rr) * 32 + kq];
      fbh[i] = *(const bf16x8*)&BhiS[(wn + i * 16 + rr) * 32 + kq];
      fbl[i] = *(const bf16x8*)&BloS[(wn + i * 16 + rr) * 32 + kq];
    }
    #pragma unroll
    for (int mi = 0; mi < 4; ++mi)
      #pragma unroll
      for (int ni = 0; ni < 4; ++ni) {
        acc[mi][ni] = __builtin_amdgcn_mfma_f32_16x16x32_bf16(fah[mi], fbh[ni], acc[mi][ni], 0, 0, 0);
        acc[mi][ni] = __builtin_amdgcn_mfma_f32_16x16x32_bf16(fah[mi], fbl[ni], acc[mi][ni], 0, 0, 0);
        acc[mi][ni] = __builtin_amdgcn_mfma_f32_16x16x32_bf16(fal[mi], fbh[ni], acc[mi][ni], 0, 0, 0);
      }
    __syncthreads();
  }

  const int er = lane >> 4, ec = lane & 15;
  #pragma unroll
  for (int mi = 0; mi < 4; ++mi)
    #pragma unroll
    for (int ni = 0; ni < 4; ++ni) {
      const int gcol = n0 + wn + ni * 16 + ec;
      #pragma unroll
      for (int e = 0; e < 4; ++e) {
        const int grow = m0 + wm + mi * 16 + er * 4 + e;
        unsafeAtomicAdd(&C[(long)z * sCz + (long)grow * ldc + gcol], acc[mi][ni][e]);
      }
    }
}

// ---------------- column softmax: row-softmax of sT[b][j][:], mask i>=j ----
__global__ __launch_bounds__(256)
void col_softmax(float* __restrict__ sT)
{
  const int T = 2048;
  const int j = blockIdx.x;
  float* row = sT + ((long)blockIdx.y * T + j) * T;
  const int tid = threadIdx.x;
  __shared__ float red[4];
  float lv[8];
  float lmax = -3.0e38f;
  #pragma unroll
  for (int p = 0; p < 2; ++p) {
    float4 v = *(const float4*)&row[tid * 4 + p * 1024];
    const int i0 = tid * 4 + p * 1024;
    lv[p * 4 + 0] = 32.f * v.x; if (i0 + 0 >= j) lmax = fmaxf(lmax, lv[p * 4 + 0]);
    lv[p * 4 + 1] = 32.f * v.y; if (i0 + 1 >= j) lmax = fmaxf(lmax, lv[p * 4 + 1]);
    lv[p * 4 + 2] = 32.f * v.z; if (i0 + 2 >= j) lmax = fmaxf(lmax, lv[p * 4 + 2]);
    lv[p * 4 + 3] = 32.f * v.w; if (i0 + 3 >= j) lmax = fmaxf(lmax, lv[p * 4 + 3]);
  }
  #pragma unroll
  for (int o = 32; o; o >>= 1) lmax = fmaxf(lmax, __shfl_down(lmax, o));
  if ((tid & 63) == 0) red[tid >> 6] = lmax;
  __syncthreads();
  const float m = fmaxf(fmaxf(red[0], red[1]), fmaxf(red[2], red[3]));
  __syncthreads();
  float zs = 0.f;
  #pragma unroll
  for (int p = 0; p < 2; ++p)
    #pragma unroll
    for (int q = 0; q < 4; ++q) {
      const int i = tid * 4 + p * 1024 + q;
      if (i >= j) zs += __expf(lv[p * 4 + q] - m);
    }
  #pragma unroll
  for (int o = 32; o; o >>= 1) zs += __shfl_down(zs, o);
  if ((tid & 63) == 0) red[tid >> 6] = zs;
  __syncthreads();
  const float rz = 1.f / (red[0] + red[1] + red[2] + red[3]);
  unsigned short* wrow = (unsigned short*)row;
  #pragma unroll
  for (int p = 0; p < 2; ++p) {
    ushort4 o;
    #pragma unroll
    for (int q = 0; q < 4; ++q) {
      const int i = tid * 4 + p * 1024 + q;
      const float wv = (i >= j) ? __expf(lv[p * 4 + q] - m) * rz : 0.f;
      ((unsigned short*)&o)[q] = f2bf(wv);
    }
    *(ushort4*)&wrow[tid * 4 + p * 1024] = o;
  }
}

// ---------------- 64x64 tiled bf16 transpose ----------------
__global__ __launch_bounds__(256)
void transpose_bf16(const unsigned short* __restrict__ in, unsigned short* __restrict__ out,
                    int ldin, int ldout, long sInZ, long sOutZ)
{
  __shared__ unsigned short tile[64][65];
  const int z = blockIdx.z;
  const int i0 = blockIdx.x * 64;
  const int j0 = blockIdx.y * 64;
  const int t = threadIdx.x;
  const int r = t >> 4;
  const int c = (t & 15) * 4;
  #pragma unroll
  for (int p = 0; p < 4; ++p) {
    const int row = j0 + r + p * 16;
    const unsigned short* ip = in + z * sInZ + (long)row * ldin + i0 + c;
    ushort4 v = *(const ushort4*)ip;
    tile[r + p * 16][c + 0] = v.x;
    tile[r + p * 16][c + 1] = v.y;
    tile[r + p * 16][c + 2] = v.z;
    tile[r + p * 16][c + 3] = v.w;
  }
  __syncthreads();
  #pragma unroll
  for (int p = 0; p < 4; ++p) {
    const int orow = i0 + r + p * 16;
    ushort4 o;
    o.x = tile[c + 0][r + p * 16];
    o.y = tile[c + 1][r + p * 16];
    o.z = tile[c + 2][r + p * 16];
    o.w = tile[c + 3][r + p * 16];
    *(ushort4*)&out[(long)z * sOutZ + (long)orow * ldout + j0 + c] = o;
  }
}

// ---------------- fp32 [R][C] -> transposed split-bf16 [C][R] ----------------
__global__ __launch_bounds__(256)
void transpose_f32_split(const float* __restrict__ in, unsigned short* __restrict__ ohi,
                         unsigned short* __restrict__ olo, int ldin, int ldout)
{
  __shared__ float tile[64][65];
  const int i0 = blockIdx.x * 64;   // input col
  const int j0 = blockIdx.y * 64;   // input row
  const int t = threadIdx.x;
  const int r = t >> 4;
  const int c = (t & 15) * 4;
  #pragma unroll
  for (int p = 0; p < 4; ++p) {
    const float* ip = in + (long)(j0 + r + p * 16) * ldin + i0 + c;
    float4 v = *(const float4*)ip;
    tile[r + p * 16][c + 0] = v.x;
    tile[r + p * 16][c + 1] = v.y;
    tile[r + p * 16][c + 2] = v.z;
    tile[r + p * 16][c + 3] = v.w;
  }
  __syncthreads();
  #pragma unroll
  for (int p = 0; p < 4; ++p) {
    const int orow = i0 + r + p * 16;
    ushort4 h, l;
    #pragma unroll
    for (int q = 0; q < 4; ++q) {
      const float v = tile[c + q][r + p * 16];
      const unsigned short hb = f2bf(v);
      ((unsigned short*)&h)[q] = hb;
      ((unsigned short*)&l)[q] = f2bf(v - bf2f(hb));
    }
    const long off = (long)orow * ldout + j0 + c;
    *(ushort4*)&ohi[off] = h;
    *(ushort4*)&olo[off] = l;
  }
}

// ---------------- fp32 -> bf16 casts ----------------
__global__ __launch_bounds__(256)
void cast_f32_bf16(const float* __restrict__ in, unsigned short* __restrict__ out, int n4)
{
  const int i = blockIdx.x * 256 + threadIdx.x;
  if (i < n4) {
    float4 v = *(const float4*)&in[i * 4];
    ushort4 o; o.x = f2bf(v.x); o.y = f2bf(v.y); o.z = f2bf(v.z); o.w = f2bf(v.w);
    *(ushort4*)&out[i * 4] = o;
  }
}

__global__ __launch_bounds__(256)
void cast_f32_split(const float* __restrict__ in, unsigned short* __restrict__ hi,
                    unsigned short* __restrict__ lo, int n4)
{
  const int i = blockIdx.x * 256 + threadIdx.x;
  if (i < n4) {
    float4 v = *(const float4*)&in[i * 4];
    ushort4 h, l;
    h.x = f2bf(v.x); l.x = f2bf(v.x - bf2f(h.x));
    h.y = f2bf(v.y); l.y = f2bf(v.y - bf2f(h.y));
    h.z = f2bf(v.z); l.z = f2bf(v.z - bf2f(h.z));
    h.w = f2bf(v.w); l.w = f2bf(v.w - bf2f(h.w));
    *(ushort4*)&hi[i * 4] = h;
    *(ushort4*)&lo[i * 4] = l;
  }
}

// ============================================================================
extern "C" void kernel_launch(void* const* d_in, const int* in_sizes, int n_in,
                              void* d_out, int out_size, void* d_ws, size_t ws_size,
                              hipStream_t stream)
{
  (void)in_sizes; (void)n_in; (void)out_size; (void)ws_size;
  const int BT = 8192;           // B*T = 4*2048
  const long TT = 2048L * 2048;  // per-batch matrix elements
  const long HB = 2048L * 1024;  // per-batch rows of h / G

  const float* x   = (const float*)d_in[0];
  const float* Wk  = (const float*)d_in[1];
  const float* Wq  = (const float*)d_in[2];
  const float* Wv  = (const float*)d_in[3];
  const float* Wl  = (const float*)d_in[4];
  const float* bl  = (const float*)d_in[5];
  const float* W1  = (const float*)d_in[6];
  const float* b1  = (const float*)d_in[7];
  const float* W2  = (const float*)d_in[8];
  const float* b2  = (const float*)d_in[9];
  const float* g1  = (const float*)d_in[10];
  const float* be1 = (const float*)d_in[11];
  const float* g2  = (const float*)d_in[12];
  const float* be2 = (const float*)d_in[13];
  float* out = (float*)d_out;

  // ---- workspace layout (time-aliased, peak 192 MB) ----
  char* ws = (char*)d_ws;
  const size_t MB = 1024 * 1024;
  unsigned short* hhi  = (unsigned short*)(ws + 0);        // [8192][1024]
  unsigned short* hlo  = (unsigned short*)(ws + 16 * MB);
  unsigned short* vT   = (unsigned short*)(ws + 32 * MB);  // [2048][8192] bf16
  unsigned short* WqTh = (unsigned short*)(ws + 64 * MB);  // [1024][2048] bf16
  unsigned short* WqTl = (unsigned short*)(ws + 68 * MB);
  unsigned short* WkTh = (unsigned short*)(ws + 72 * MB);
  unsigned short* WkTl = (unsigned short*)(ws + 76 * MB);
  float*          MTf  = (float*)(ws + 80 * MB);           // [1024][1024] f32
  unsigned short* MTh  = (unsigned short*)(ws + 84 * MB);  // [1024][1024] bf16
  unsigned short* MTl  = (unsigned short*)(ws + 86 * MB);
  unsigned short* Wvb  = (unsigned short*)(ws + 88 * MB);  // [2048][1024] bf16
  unsigned short* Ghi  = (unsigned short*)(ws + 96 * MB);  // [8192][1024] bf16
  unsigned short* Glo  = (unsigned short*)(ws + 112 * MB);
  float*          Gf   = (float*)(ws + 160 * MB);          // [8192][1024] f32
  float*          sT   = (float*)(ws + 128 * MB);          // 4x[2048][2048] f32
  // post-scores aliases:
  unsigned short* w    = (unsigned short*)(ws + 64 * MB);  // 4x[2048][2048] bf16
  unsigned short* att  = (unsigned short*)(ws + 96 * MB);  // [8192][2048] bf16
  unsigned short* Wlb  = (unsigned short*)(ws + 0);
  unsigned short* W1b  = (unsigned short*)(ws + 4 * MB);
  unsigned short* W2b  = (unsigned short*)(ws + 12 * MB);
  unsigned short* h2   = (unsigned short*)(ws + 20 * MB);  // [8192][1024] bf16
  unsigned short* ff1  = (unsigned short*)(ws + 128 * MB); // [8192][4096] bf16

  // 1. LN1 -> split h
  layernorm_k<2><<<dim3(BT), 256, 0, stream>>>(x, g1, be1, hhi, hlo);

  // 2. weight transposes/casts:  Wq,Wk [2048][1024] -> [1024][2048] split
  transpose_f32_split<<<dim3(16, 32), 256, 0, stream>>>(Wq, WqTh, WqTl, 1024, 2048);
  transpose_f32_split<<<dim3(16, 32), 256, 0, stream>>>(Wk, WkTh, WkTl, 1024, 2048);
  cast_f32_bf16<<<dim3(2048), 256, 0, stream>>>(Wv, Wvb, 2097152 / 4);

  // 3. MT[c2][c1] = sum_d Wq[d][c2] Wk[d][c1]  (K=2048, K-split x8, atomic f32)
  zero_f32<<<dim3(1024), 256, 0, stream>>>(MTf, 1024 * 1024 / 4);
  gemm_split2<0><<<dim3(8 * 8, 8, 1), 256, 0, stream>>>(WqTh, WqTl, WkTh, WkTl, MTf,
                                                        2048, 8, 2048, 2048, 1024, 0, 0, 0);
  cast_f32_split<<<dim3(1024), 256, 0, stream>>>(MTf, MTh, MTl, 1024 * 1024 / 4);

  // 4. G[i][c2] = sum_c1 h[i][c1] MT[c2][c1]  (K=1024, K-split x2, atomic f32)
  zero_f32<<<dim3(8192), 256, 0, stream>>>(Gf, 8192 * 1024 / 4);
  gemm_split2<0><<<dim3(8 * 2, 64, 1), 256, 0, stream>>>(hhi, hlo, MTh, MTl, Gf,
                                                         1024, 2, 1024, 1024, 1024, 0, 0, 0);
  cast_f32_split<<<dim3(8192), 256, 0, stream>>>(Gf, Ghi, Glo, 8192 * 1024 / 4);

  // 5. vT = (h @ Wv^T)^T  (plain bf16, transposed out)
  gemm_bt<1, 0, 0, 0, 1, 0><<<dim3(16, 64, 1), 256, 0, stream>>>(hhi, Wvb, (void*)vT,
                                                                 nullptr, nullptr,
                                                                 1024, 1024, 1024, 8192, 0, 0, 0);

  // 6. sT[b][j][i] = sum_c h[j][c] G[i][c]  (triangular, K=1024, K-split x2)
  zero_f32<<<dim3(16384), 256, 0, stream>>>(sT, 4 * 2048 * 2048 / 4);
  gemm_split2<1><<<dim3(136 * 2, 1, 4), 256, 0, stream>>>(hhi, hlo, Ghi, Glo, sT,
                                                          1024, 2, 1024, 1024, 2048, HB, HB, TT);

  // 7. column softmax (mask i>=j), in-place bf16 wT
  col_softmax<<<dim3(2048, 4), 256, 0, stream>>>(sT);

  // 8. transpose wT -> w  (bf16 rows live in fp32-row storage: ld 4096)
  transpose_bf16<<<dim3(32, 32, 4), 256, 0, stream>>>((const unsigned short*)sT, w,
                                                      4096, 2048, 2048L * 4096, TT);

  // 9. weight casts for the tail (h dead now)
  cast_f32_bf16<<<dim3(2048), 256, 0, stream>>>(Wl, Wlb, 2097152 / 4);
  cast_f32_bf16<<<dim3(4096), 256, 0, stream>>>(W1, W1b, 4194304 / 4);
  cast_f32_bf16<<<dim3(4096), 256, 0, stream>>>(W2, W2b, 4194304 / 4);

  // 10. att = w @ vT^T (batched, K truncated at the causal diagonal)
  gemm_bt<1, 0, 0, 0, 0, 1><<<dim3(16, 16, 4), 256, 0, stream>>>(w, vT, (void*)att, nullptr, nullptr,
                                                                 2048, 2048, 8192, 2048, TT, 2048, TT);

  // 11. d_out = x + relu(att @ Wl^T + bl)
  gemm_bt<0, 1, 1, 1, 0, 0><<<dim3(8, 64, 1), 256, 0, stream>>>(att, Wlb, (void*)out, bl, x,
                                                                2048, 2048, 2048, 1024, 0, 0, 0);

  // 12. LN2
  layernorm_k<1><<<dim3(BT), 256, 0, stream>>>(out, g2, be2, h2, nullptr);

  // 13. ff1 = relu(h2 @ W1^T + b1)
  gemm_bt<1, 1, 1, 0, 0, 0><<<dim3(32, 64, 1), 256, 0, stream>>>(h2, W1b, (void*)ff1, b1, nullptr,
                                                                 1024, 1024, 1024, 4096, 0, 0, 0);

  // 14. d_out += ff1 @ W2^T + b2
  gemm_bt<0, 1, 0, 1, 0, 0><<<dim3(8, 64, 1), 256, 0, stream>>>(ff1, W2b, (void*)out, b2, out,
                                                                4096, 4096, 4096, 1024, 0, 0, 0);
}